// Round 14
// baseline (429.325 us; speedup 1.0000x reference)
//
#include <hip/hip_runtime.h>

typedef unsigned short u16;
typedef unsigned int u32;
typedef unsigned long long u64;
using f32x4 = __attribute__((ext_vector_type(4))) float;
using bf16x8 = __attribute__((ext_vector_type(8))) short;

#define CIN 128
#define COUT 128
#define BM 128
#define LDA 136  // padded LDS row stride for Asub in fallback kernel only

__device__ inline u16 bf16rn(float f) {
    union { float f; u32 u; } v; v.f = f;
    u32 u = v.u;
    u += 0x7FFFu + ((u >> 16) & 1u);   // round-to-nearest-even
    return (u16)(u >> 16);
}

// ---------------- fallback-path precasts (also used as prep_k bodies) ----------------
__global__ void precast_feats_k(const float* __restrict__ in, u16* __restrict__ out, int total8) {
    int i = blockIdx.x * blockDim.x + threadIdx.x;
    if (i >= total8) return;
    const float4* p = (const float4*)in + 2 * (size_t)i;
    float4 a = p[0], b = p[1];
    u32 o0 = (u32)bf16rn(a.x) | ((u32)bf16rn(a.y) << 16);
    u32 o1 = (u32)bf16rn(a.z) | ((u32)bf16rn(a.w) << 16);
    u32 o2 = (u32)bf16rn(b.x) | ((u32)bf16rn(b.y) << 16);
    u32 o3 = (u32)bf16rn(b.z) | ((u32)bf16rn(b.w) << 16);
    ((uint4*)out)[i] = make_uint4(o0, o1, o2, o3);
}

// Wt fragment-linear layout: Wt[k][frag][lane][e], frag = cn*4+kk (32 frags).
// Element = W[k][c][d], d = cn*16 + (lane&15), c = kk*32 + (lane>>4)*8 + e.
// LDS staging is a pure linear memcpy; inner ds_read_b128 at lane*16B is
// conflict-free (verified r11: SQ_LDS_BANK_CONFLICT 5.4M -> 0).
__global__ void precast_w_k(const float* __restrict__ W, u16* __restrict__ Wt, int total) {
    int i = blockIdx.x * blockDim.x + threadIdx.x;
    if (i >= total) return;
    int k = i >> 14;
    int rem = i & 16383;
    int f = rem >> 9;          // frag 0..31
    int l = (rem >> 3) & 63;   // lane
    int e = rem & 7;
    int cn = f >> 2, kk = f & 3;
    int d = cn * 16 + (l & 15);
    int c = kk * 32 + ((l >> 4) << 3) + e;
    Wt[i] = bf16rn(W[(k << 14) + (c << 7) + d]);
}

// ---------------- fused prep: precast feats || precast W || hist ----------------
__global__ void prep_k(const float* __restrict__ feats, const float* __restrict__ W,
                       const int* __restrict__ oi, const int* __restrict__ valid,
                       u16* __restrict__ fb, u16* __restrict__ Wt,
                       int* __restrict__ cnt, int* __restrict__ pos,
                       int* __restrict__ bc0, int* __restrict__ bc1,
                       int total8, int totalw, int N, int E, int b0, int b1) {
    const int blk = blockIdx.x;
    const int tid = threadIdx.x;
    if (blk < b0) {
        int i = blk * 256 + tid;
        if (i >= total8) return;
        const float4* p = (const float4*)feats + 2 * (size_t)i;
        float4 a = p[0], q = p[1];
        u32 o0 = (u32)bf16rn(a.x) | ((u32)bf16rn(a.y) << 16);
        u32 o1 = (u32)bf16rn(a.z) | ((u32)bf16rn(a.w) << 16);
        u32 o2 = (u32)bf16rn(q.x) | ((u32)bf16rn(q.y) << 16);
        u32 o3 = (u32)bf16rn(q.z) | ((u32)bf16rn(q.w) << 16);
        ((uint4*)fb)[i] = make_uint4(o0, o1, o2, o3);
    } else if (blk < b0 + b1) {
        int i = (blk - b0) * 256 + tid;
        if (i >= totalw) return;
        int k = i >> 14;
        int rem = i & 16383;
        int f = rem >> 9;
        int l = (rem >> 3) & 63;
        int e = rem & 7;
        int cn = f >> 2, kk = f & 3;
        int d = cn * 16 + (l & 15);
        int c = kk * 32 + ((l >> 4) << 3) + e;
        Wt[i] = bf16rn(W[(k << 14) + (c << 7) + d]);
    } else {
        const int b = blk - b0 - b1;            // local hist block index
        const int e = b * 256 + tid;
        const int k0 = (b * 256) / N;
        bool v = false; bool g = false;
        if (e < E) {
            v = valid[e] > 0;
            g = (e >= (k0 + 1) * N);
            if (v) pos[e] = atomicAdd(&cnt[oi[e]], 1);
        }
        const int lane = tid & 63, wid = tid >> 6;
        u64 m0 = __ballot(v && !g);
        u64 m1 = __ballot(v && g);
        __shared__ int wt[4][2];
        if (lane == 0) { wt[wid][0] = __popcll(m0); wt[wid][1] = __popcll(m1); }
        __syncthreads();
        if (tid == 0) bc0[b] = wt[0][0] + wt[1][0] + wt[2][0] + wt[3][0];
        if (tid == 1) bc1[b] = wt[0][1] + wt[1][1] + wt[2][1] + wt[3][1];
    }
}

// ---------------- fallback-path hist (unfused) ----------------
__global__ void hist_k(const int* __restrict__ oi, const int* __restrict__ valid,
                       int* __restrict__ cnt, int* __restrict__ pos,
                       int* __restrict__ bc0, int* __restrict__ bc1, int N, int E) {
    const int tid = threadIdx.x;
    const int b = blockIdx.x;
    const int e = b * 256 + tid;
    const int k0 = (b * 256) / N;
    bool v = false; bool g = false;
    if (e < E) {
        v = valid[e] > 0;
        g = (e >= (k0 + 1) * N);
        if (v) pos[e] = atomicAdd(&cnt[oi[e]], 1);
    }
    const int lane = tid & 63, wid = tid >> 6;
    u64 m0 = __ballot(v && !g);
    u64 m1 = __ballot(v && g);
    __shared__ int wt[4][2];
    if (lane == 0) { wt[wid][0] = __popcll(m0); wt[wid][1] = __popcll(m1); }
    __syncthreads();
    if (tid == 0) bc0[b] = wt[0][0] + wt[1][0] + wt[2][0] + wt[3][0];
    if (tid == 1) bc1[b] = wt[0][1] + wt[1][1] + wt[2][1] + wt[3][1];
}

// ---- hierarchical exclusive scan of cnt[N] -> offs[N+1] ----
__global__ void scan_sum_k(const int* __restrict__ cnt, int* __restrict__ bsum, int N) {
    __shared__ int red[256];
    int t = threadIdx.x;
    int i = blockIdx.x * 256 + t;
    red[t] = (i < N) ? cnt[i] : 0;
    __syncthreads();
    #pragma unroll
    for (int d = 128; d > 0; d >>= 1) {
        if (t < d) red[t] += red[t + d];
        __syncthreads();
    }
    if (t == 0) bsum[blockIdx.x] = red[0];
}

__global__ void scan_top_k(int* __restrict__ bsum, int nb) {
    __shared__ int part[1024];
    int t = threadIdx.x;
    int v = (t < nb) ? bsum[t] : 0;
    part[t] = v;
    __syncthreads();
    for (int d = 1; d < 1024; d <<= 1) {
        int x = (t >= d) ? part[t - d] : 0;
        __syncthreads();
        part[t] += x;
        __syncthreads();
    }
    if (t < nb) bsum[t] = part[t] - v;   // exclusive
}

// ---------------- fused scan_apply || kscan (block-range split) ----------------
__global__ void scan_apply_kscan_k(const int* __restrict__ cnt, const int* __restrict__ bsum,
                                   int* __restrict__ offs,
                                   const int* __restrict__ bc0, const int* __restrict__ bc1,
                                   int* __restrict__ base0, int* __restrict__ base1,
                                   int* __restrict__ kcount, int N, int nb) {
    const int t = threadIdx.x;
    __shared__ int part[256];
    if ((int)blockIdx.x < nb) {
        int i = blockIdx.x * 256 + t;
        int v = (i < N) ? cnt[i] : 0;
        part[t] = v;
        __syncthreads();
        #pragma unroll
        for (int d = 1; d < 256; d <<= 1) {
            int x = (t >= d) ? part[t - d] : 0;
            __syncthreads();
            part[t] += x;
            __syncthreads();
        }
        int base = bsum[blockIdx.x];
        if (i < N) {
            int excl = base + part[t] - v;
            offs[i] = excl;
            if (i == N - 1) offs[N] = excl + v;
        }
    } else {
        const int k = blockIdx.x - nb;
        const int blo = (k * N) / 256;
        const int bhi = ((k + 1) * N - 1) / 256;
        const int len = bhi - blo + 1;        // <= 256 (guarded host-side)
        const int b = blo + t;
        int k0b = 0, contrib = 0;
        const bool inr = (t < len);
        if (inr) {
            k0b = (b * 256) / N;
            contrib = (k0b == k) ? bc0[b] : bc1[b];
        }
        part[t] = contrib;
        __syncthreads();
        #pragma unroll
        for (int d = 1; d < 256; d <<= 1) {
            int x = (t >= d) ? part[t - d] : 0;
            __syncthreads();
            part[t] += x;
            __syncthreads();
        }
        if (inr) {
            int excl = part[t] - contrib;
            if (k0b == k) base0[b] = excl; else base1[b] = excl;
            if (t == len - 1) kcount[k] = part[t];
        }
    }
}

// ---------------- rank: fully atomic-free ----------------
__global__ void rank_k(const int* __restrict__ oi, const int* __restrict__ ini,
                       const int* __restrict__ valid, const int* __restrict__ pos,
                       const int* __restrict__ offs,
                       const int* __restrict__ base0, const int* __restrict__ base1,
                       int* __restrict__ cin_arr, int* __restrict__ cpos_arr,
                       int N, int E, int cap) {
    const int tid = threadIdx.x;
    const int b = blockIdx.x;
    const int e = b * 256 + tid;
    const int k0 = (b * 256) / N;
    bool v = false; int k = 0, n = 0, ii = 0, p = 0;
    if (e < E) {
        v = valid[e] > 0;
        k = (e >= (k0 + 1) * N) ? k0 + 1 : k0;
        if (v) { n = oi[e]; ii = ini[e]; p = pos[e]; }
    }
    const int g = k - k0;   // 0 or 1
    const int lane = tid & 63, wid = tid >> 6;
    u64 m0 = __ballot(v && g == 0);
    u64 m1 = __ballot(v && g == 1);
    u64 lt = (1ull << lane) - 1ull;
    int r0 = __popcll(m0 & lt);
    int r1 = __popcll(m1 & lt);
    __shared__ int wt[4][2];
    if (lane == 0) { wt[wid][0] = __popcll(m0); wt[wid][1] = __popcll(m1); }
    __syncthreads();
    if (v) {
        int wbase = 0;
        #pragma unroll
        for (int w2 = 0; w2 < 4; ++w2) if (w2 < wid) wbase += wt[w2][g];
        int kb = g ? base1[b] : base0[b];
        int slot = kb + wbase + (g ? r1 : r0);
        int pg = offs[n] + p;
        cin_arr[k * N + slot] = ii;
        cpos_arr[k * N + slot] = (pg < cap) ? pg : (cap + n);
    }
}

// ---------------- phase A: persistent-per-k gather + GEMM + sorted store ----------------
// Grid = nbk x K. Each block stages W[k] ONCE (32 KB, fragment-linear,
// conflict-free), then its 8 waves grid-stride over 16-row chunks with a
// manual prefetch double-buffer: while chunk c runs its 32 MFMAs + store,
// the gather for chunk c+stride is in flight. No barrier after staging
// (Bsub read-only). ~830 rows amortize each staging event (6.5x less than
// the old 128-rows-per-block structure).
// msg row layout: word w = 4*l15 + q holds packed bf16 cols (l15+32q, l15+32q+16)
__launch_bounds__(512, 6)
__global__ void convA_k(const u16* __restrict__ fb, const u16* __restrict__ Wt,
                        const int* __restrict__ cin_arr, const int* __restrict__ cpos_arr,
                        const int* __restrict__ kcount, u32* __restrict__ msg,
                        float* __restrict__ out, int N, int cap, int nbk)
{
    const int k = blockIdx.y;
    const int kc = kcount[k];

    __shared__ __align__(16) u16 Bsub[COUT * CIN];   // 32 KB, fragment-linear

    const int tid = threadIdx.x;
    const int wave = tid >> 6, lane = tid & 63;
    const int l15 = lane & 15, l4 = lane >> 4;
    const int base = k * N;

    // stage W[k] (fragment-order, 32 KB) into LDS: pure linear memcpy
    {
        const u16* wk = Wt + ((size_t)k << 14);
        #pragma unroll
        for (int j = 0; j < 4; ++j)
            *(uint4*)(Bsub + j * 4096 + tid * 8) = *(const uint4*)(wk + j * 4096 + tid * 8);
    }
    __syncthreads();

    const int nch = (kc + 15) >> 4;          // 16-row chunks for this k
    const int wstep = nbk * 8;               // total waves servicing this k
    int c = blockIdx.x * 8 + wave;           // this wave's first chunk
    if (c >= nch) return;                    // wave-uniform

    // prefetch chunk c
    bf16x8 a0[4];
    {
        int r0 = c * 16 + l15;
        int i0 = cin_arr[base + min(r0, kc - 1)];
        if (r0 >= kc) i0 = 0;
        const u16* pa = fb + (size_t)i0 * CIN + l4 * 8;
        #pragma unroll
        for (int kk = 0; kk < 4; ++kk)
            a0[kk] = *(const bf16x8*)(pa + kk * 32);
    }

    while (true) {
        const int cnext = c + wstep;
        const bool has = (cnext < nch);      // wave-uniform

        // prefetch next chunk while current computes
        bf16x8 an[4];
        if (has) {
            int r1 = cnext * 16 + l15;
            int i1 = cin_arr[base + min(r1, kc - 1)];
            if (r1 >= kc) i1 = 0;
            const u16* pa = fb + (size_t)i1 * CIN + l4 * 8;
            #pragma unroll
            for (int kk = 0; kk < 4; ++kk)
                an[kk] = *(const bf16x8*)(pa + kk * 32);
        }

        // compute current chunk: 16 rows x 128 cols
        f32x4 acc[8];
        #pragma unroll
        for (int y = 0; y < 8; ++y)
            acc[y] = (f32x4){0.f, 0.f, 0.f, 0.f};
        #pragma unroll
        for (int kk = 0; kk < 4; ++kk) {
            #pragma unroll
            for (int cn = 0; cn < 8; ++cn) {
                bf16x8 b = *(const bf16x8*)(Bsub + (((cn << 2) + kk) << 9) + lane * 8);
                acc[cn] = __builtin_amdgcn_mfma_f32_16x16x32_bf16(a0[kk], b, acc[cn], 0, 0, 0);
            }
        }

        // epilogue: sorted msg store (or atomic fallback)
        #pragma unroll
        for (int j = 0; j < 4; ++j) {
            int rl = c * 16 + l4 * 4 + j;
            if (rl >= kc) continue;
            int v = cpos_arr[base + rl];   // 16 lanes share each addr -> broadcast
            if (v < cap) {
                u32 w0 = (u32)bf16rn(acc[0][j]) | ((u32)bf16rn(acc[1][j]) << 16);
                u32 w1 = (u32)bf16rn(acc[2][j]) | ((u32)bf16rn(acc[3][j]) << 16);
                u32 w2 = (u32)bf16rn(acc[4][j]) | ((u32)bf16rn(acc[5][j]) << 16);
                u32 w3 = (u32)bf16rn(acc[6][j]) | ((u32)bf16rn(acc[7][j]) << 16);
                *(uint4*)(msg + (size_t)v * 64 + 4 * l15) = make_uint4(w0, w1, w2, w3);
            } else {
                int n = v - cap;
                float* dst = out + (size_t)n * COUT + l15;
                #pragma unroll
                for (int cn = 0; cn < 8; ++cn)
                    atomicAdd(dst + cn * 16, acc[cn][j]);
            }
        }

        if (!has) break;
        #pragma unroll
        for (int kk = 0; kk < 4; ++kk) a0[kk] = an[kk];
        c = cnext;
    }
}

// ---------------- phase B (wmode=1): uint4 segment-sum + fused stats ----------------
__global__ void convB_stats_k(const u32* __restrict__ msg, const int* __restrict__ offs,
                              float* __restrict__ out, float* __restrict__ stats,
                              int N, int cap, int nblk)
{
    const int tid = threadIdx.x;
    const int wave = tid >> 6, lane = tid & 63;
    const int sub = lane >> 4, l15 = lane & 15;
    const int colA = l15 + 32 * sub;
    float sA = 0.f, qA = 0.f, sB = 0.f, qB = 0.f;

    for (int n = blockIdx.x * 4 + wave; n < N; n += nblk * 4) {
        int s = min(offs[n], cap), e = min(offs[n + 1], cap);
        float a0 = 0.f, a1 = 0.f, a2 = 0.f, a3 = 0.f;
        float b0 = 0.f, b1 = 0.f, b2 = 0.f, b3 = 0.f;
        for (int r = s; r < e; r += 4) {
            int ent = r + sub;
            uint4 v = make_uint4(0u, 0u, 0u, 0u);
            if (ent < e) v = *(const uint4*)(msg + (size_t)ent * 64 + 4 * l15);
            a0 += __uint_as_float(v.x << 16); b0 += __uint_as_float(v.x & 0xFFFF0000u);
            a1 += __uint_as_float(v.y << 16); b1 += __uint_as_float(v.y & 0xFFFF0000u);
            a2 += __uint_as_float(v.z << 16); b2 += __uint_as_float(v.z & 0xFFFF0000u);
            a3 += __uint_as_float(v.w << 16); b3 += __uint_as_float(v.w & 0xFFFF0000u);
        }
        #define RED4(x) { x += __shfl_xor(x, 16, 64); x += __shfl_xor(x, 32, 64); }
        RED4(a0) RED4(a1) RED4(a2) RED4(a3)
        RED4(b0) RED4(b1) RED4(b2) RED4(b3)
        #undef RED4
        float va = (sub == 0) ? a0 : (sub == 1) ? a1 : (sub == 2) ? a2 : a3;
        float vb = (sub == 0) ? b0 : (sub == 1) ? b1 : (sub == 2) ? b2 : b3;
        float* po = out + (size_t)n * COUT;
        po[colA]      = va;
        po[colA + 16] = vb;
        sA += va; qA += va * va;
        sB += vb; qB += vb * vb;
    }

    __shared__ float st[4][64][4];
    st[wave][lane][0] = sA; st[wave][lane][1] = qA;
    st[wave][lane][2] = sB; st[wave][lane][3] = qB;
    __syncthreads();
    int lane2 = tid >> 2, slot = tid & 3;
    float sum = st[0][lane2][slot] + st[1][lane2][slot]
              + st[2][lane2][slot] + st[3][lane2][slot];
    int colb = (lane2 & 15) + 32 * (lane2 >> 4) + ((slot >= 2) ? 16 : 0);
    atomicAdd(&stats[((slot & 1) ? 128 : 0) + colb], sum);
}

// ---------------- phase B (wmode=0): += segment-sum (composes with atomics) ----
__global__ void convB_k(const u32* __restrict__ msg, const int* __restrict__ offs,
                        float* __restrict__ out, int N, int cap)
{
    int wave = threadIdx.x >> 6, lane = threadIdx.x & 63;
    int n = blockIdx.x * 4 + wave;
    if (n >= N) return;
    int s = min(offs[n], cap), e = min(offs[n + 1], cap);
    float a0 = 0.f, a1 = 0.f;
    int r = s;
    for (; r + 2 <= e; r += 2) {
        u32 v0 = msg[(size_t)r * 64 + lane];
        u32 v1 = msg[(size_t)(r + 1) * 64 + lane];
        a0 += __uint_as_float(v0 << 16) + __uint_as_float(v1 << 16);
        a1 += __uint_as_float(v0 & 0xFFFF0000u) + __uint_as_float(v1 & 0xFFFF0000u);
    }
    if (r < e) {
        u32 v0 = msg[(size_t)r * 64 + lane];
        a0 += __uint_as_float(v0 << 16);
        a1 += __uint_as_float(v0 & 0xFFFF0000u);
    }
    int c0 = (lane >> 2) + ((lane & 3) << 5);
    float* po = out + (size_t)n * COUT;
    po[c0]      += a0;
    po[c0 + 16] += a1;
}

// ---------------- fallback atomic conv (frag-linear Wt) ----------------
__launch_bounds__(256, 2)
__global__ void conv_k(const u16* __restrict__ fb, const u16* __restrict__ Wt,
                       const int* __restrict__ in_idx, const int* __restrict__ out_idx,
                       const int* __restrict__ valid, float* __restrict__ out, int N)
{
    __shared__ __align__(16) u16 Asub[BM * LDA];
    __shared__ __align__(16) u16 Bsub[COUT * CIN];   // fragment-linear
    __shared__ int orow[BM];

    const int tile = blockIdx.x;
    const int k = blockIdx.y;
    const int tid = threadIdx.x;
    const int m0 = tile * BM;

    {
        const u16* wk = Wt + ((size_t)k << 14);
        #pragma unroll
        for (int j = 0; j < 8; ++j)
            *(uint4*)(Bsub + j * 2048 + tid * 8) = *(const uint4*)(wk + j * 2048 + tid * 8);
    }
    {
        int r = tid >> 1, half = tid & 1;
        int m = m0 + r;
        int act = 0, ii = 0, oi = -1;
        if (m < N) {
            int base = k * N + m;
            act = valid[base];
            ii  = in_idx[base];
            oi  = out_idx[base];
        }
        if (half == 0) orow[r] = (m < N && act > 0) ? oi : -1;
        if (m < N && act > 0) {
            const u16* src = fb + (size_t)ii * CIN + half * 64;
            u16* dst = Asub + r * LDA + half * 64;
            #pragma unroll
            for (int j = 0; j < 8; ++j)
                *(uint4*)(dst + j * 8) = *(const uint4*)(src + j * 8);
        }
    }
    __syncthreads();

    const int wave = tid >> 6, lane = tid & 63;
    const int l15 = lane & 15, l4 = lane >> 4;

    f32x4 acc[2][8];
    #pragma unroll
    for (int x = 0; x < 2; ++x)
        #pragma unroll
        for (int y = 0; y < 8; ++y)
            acc[x][y] = (f32x4){0.f, 0.f, 0.f, 0.f};

    #pragma unroll
    for (int kk = 0; kk < 4; ++kk) {
        const int coff = kk * 32 + l4 * 8;
        bf16x8 a0 = *(const bf16x8*)(Asub + (wave * 32 + l15) * LDA + coff);
        bf16x8 a1 = *(const bf16x8*)(Asub + (wave * 32 + 16 + l15) * LDA + coff);
        #pragma unroll
        for (int cn = 0; cn < 8; ++cn) {
            bf16x8 b = *(const bf16x8*)(Bsub + (((cn << 2) + kk) << 9) + lane * 8);
            acc[0][cn] = __builtin_amdgcn_mfma_f32_16x16x32_bf16(a0, b, acc[0][cn], 0, 0, 0);
            acc[1][cn] = __builtin_amdgcn_mfma_f32_16x16x32_bf16(a1, b, acc[1][cn], 0, 0, 0);
        }
    }

    #pragma unroll
    for (int rm = 0; rm < 2; ++rm) {
        #pragma unroll
        for (int j = 0; j < 4; ++j) {
            int rl = wave * 32 + rm * 16 + l4 * 4 + j;
            int od = orow[rl];
            if (od >= 0) {
                float* dst = out + (size_t)od * COUT + l15;
                #pragma unroll
                for (int cn = 0; cn < 8; ++cn)
                    atomicAdd(dst + cn * 16, acc[rm][cn][j]);
            }
        }
    }
}

// ---------------- stats / BN+GELU ----------------
__global__ void stats_k(const float* __restrict__ out, float* __restrict__ stats, int N) {
    const int tid = threadIdx.x;
    const int col = tid & 127;
    const int pr = tid >> 7;
    float s = 0.f, sq = 0.f;
    for (int r = blockIdx.x * 2 + pr; r < N; r += gridDim.x * 2) {
        float v = out[(size_t)r * COUT + col];
        s += v; sq += v * v;
    }
    __shared__ float red[512];
    red[tid] = s;
    red[256 + tid] = sq;
    __syncthreads();
    if (tid < 128) {
        atomicAdd(&stats[col],       red[tid] + red[tid + 128]);
        atomicAdd(&stats[128 + col], red[256 + tid] + red[384 + tid]);
    }
}

__global__ void finalize_k(float* __restrict__ stats, const float* __restrict__ gamma,
                           const float* __restrict__ beta, float invN) {
    int c = threadIdx.x;   // 128 threads
    float mean = stats[c] * invN;
    float var = stats[128 + c] * invN - mean * mean;
    float sc = rsqrtf(var + 1e-5f) * gamma[c];
    stats[256 + c] = sc;
    stats[384 + c] = beta[c] - mean * sc;
}

__global__ void bngelu_k(float* __restrict__ out, const float* __restrict__ stats, int total4) {
    int i = blockIdx.x * blockDim.x + threadIdx.x;
    if (i >= total4) return;
    float4 v = ((const float4*)out)[i];
    int cb = (i << 2) & 127;
    float r[4] = {v.x, v.y, v.z, v.w};
    #pragma unroll
    for (int e = 0; e < 4; ++e) {
        int c = cb + e;
        float y = r[e] * stats[256 + c] + stats[384 + c];
        r[e] = 0.5f * y * (1.0f + erff(y * 0.70710678118f));
    }
    ((float4*)out)[i] = make_float4(r[0], r[1], r[2], r[3]);
}

extern "C" void kernel_launch(void* const* d_in, const int* in_sizes, int n_in,
                              void* d_out, int out_size, void* d_ws, size_t ws_size,
                              hipStream_t stream) {
    const float* feats  = (const float*)d_in[0];
    const float* W      = (const float*)d_in[1];
    const float* gamma  = (const float*)d_in[2];
    const float* beta   = (const float*)d_in[3];
    const int*   in_idx = (const int*)d_in[4];
    const int*   outidx = (const int*)d_in[5];
    const int*   valid  = (const int*)d_in[6];
    const int N = in_sizes[0] / CIN;          // 40000
    const int K = in_sizes[1] / (CIN * COUT); // 27
    const int E = K * N;
    float* out = (float*)d_out;

    const int nb  = (N + 255) / 256;          // scan blocks (157) — must be <= 1024
    const int nbE = (E + 255) / 256;          // entry blocks (4219)

    const size_t fbB   = ((size_t)N * CIN * 2 + 255) & ~255ull;
    const size_t WtB   = ((size_t)K * CIN * COUT * 2 + 255) & ~255ull;
    const size_t cinB  = ((size_t)E * 4 + 255) & ~255ull;
    const size_t cposB = cinB;
    const size_t posB  = cinB;                                   // pos[E]
    const size_t cntB  = ((size_t)N * 4 + 255) & ~255ull;       // cnt[N]
    const size_t kcB   = 256;                                    // kcount[K]
    const size_t stB   = 2048;                                   // stats[512]
    const size_t offsB = ((size_t)(N + 1) * 4 + 255) & ~255ull;
    const size_t bsB   = ((size_t)nb * 4 + 255) & ~255ull;       // block sums
    const size_t nbEB  = ((size_t)nbE * 4 + 255) & ~255ull;      // bc0/bc1/base0/base1
    const size_t fixedB = fbB + WtB + cinB + cposB + posB + cntB + kcB + stB + offsB
                        + bsB + 4 * nbEB + 1024;

    int total8 = N * CIN / 8;
    int totalw = K * CIN * COUT;

    if (ws_size >= fixedB + (size_t)1024 * 256 && nb <= 1024 && nb + 1 <= 256) {
        long long capL = ((long long)ws_size - (long long)fixedB) / 256;
        if (capL > (long long)E) capL = E;
        const int cap = (int)capL;
        const int wmode = (cap >= E) ? 1 : 0;   // no overflow atomics possible

        char* w = (char*)d_ws;
        u32* msg      = (u32*)w;  w += (size_t)cap * 256;
        u16* fb       = (u16*)w;  w += fbB;
        u16* Wt       = (u16*)w;  w += WtB;
        int* cin_arr  = (int*)w;  w += cinB;
        int* cpos_arr = (int*)w;  w += cposB;
        int* pos      = (int*)w;  w += posB;
        int* cnt      = (int*)w;  w += cntB;   // cnt | kcount | stats contiguous
        int* kcount   = (int*)w;  w += kcB;
        float* stats  = (float*)w; w += stB;
        int* offs     = (int*)w;  w += offsB;
        int* bsum     = (int*)w;  w += bsB;
        int* bc0      = (int*)w;  w += nbEB;
        int* bc1      = (int*)w;  w += nbEB;
        int* base0    = (int*)w;  w += nbEB;
        int* base1    = (int*)w;

        if (!wmode)
            hipMemsetAsync(out, 0, (size_t)N * COUT * sizeof(float), stream);
        hipMemsetAsync(cnt, 0, cntB + kcB + stB, stream);

        const int b0 = (total8 + 255) / 256;
        const int b1 = (totalw + 255) / 256;
        prep_k<<<b0 + b1 + nbE, 256, 0, stream>>>(feats, W, outidx, valid, fb, Wt,
                                                  cnt, pos, bc0, bc1,
                                                  total8, totalw, N, E, b0, b1);
        scan_sum_k<<<nb, 256, 0, stream>>>(cnt, bsum, N);
        scan_top_k<<<1, 1024, 0, stream>>>(bsum, nb);
        scan_apply_kscan_k<<<nb + K, 256, 0, stream>>>(cnt, bsum, offs, bc0, bc1,
                                                       base0, base1, kcount, N, nb);
        rank_k<<<nbE, 256, 0, stream>>>(outidx, in_idx, valid, pos, offs,
                                        base0, base1, cin_arr, cpos_arr, N, E, cap);

        const int nbk = 24;   // persistent blocks per k (648 total ~ 2.5/CU)
        dim3 gA(nbk, K);
        convA_k<<<gA, 512, 0, stream>>>(fb, Wt, cin_arr, cpos_arr, kcount, msg, out,
                                        N, cap, nbk);

        if (wmode) {
            const int nblk = 2048;
            convB_stats_k<<<nblk, 256, 0, stream>>>(msg, offs, out, stats, N, cap, nblk);
        } else {
            convB_k<<<(N + 3) / 4, 256, 0, stream>>>(msg, offs, out, N, cap);
            stats_k<<<256, 256, 0, stream>>>(out, stats, N);
        }

        finalize_k<<<1, 128, 0, stream>>>(stats, gamma, beta, 1.0f / (float)N);
        bngelu_k<<<(N * COUT / 4 + 255) / 256, 256, 0, stream>>>(out, stats, N * COUT / 4);
    } else {
        // minimal-ws fallback: atomic path (~11.4 MB)
        u16* fb = (u16*)d_ws;
        u16* Wt = fb + (size_t)N * CIN;
        float* stats = (float*)(Wt + (size_t)K * CIN * COUT);

        hipMemsetAsync(out, 0, (size_t)N * COUT * sizeof(float), stream);
        hipMemsetAsync(stats, 0, 256 * sizeof(float), stream);

        precast_feats_k<<<(total8 + 255) / 256, 256, 0, stream>>>(feats, fb, total8);
        precast_w_k<<<(totalw + 255) / 256, 256, 0, stream>>>(W, Wt, totalw);

        dim3 g((N + BM - 1) / BM, K);
        conv_k<<<g, 256, 0, stream>>>(fb, Wt, in_idx, outidx, valid, out, N);

        stats_k<<<256, 256, 0, stream>>>(out, stats, N);
        finalize_k<<<1, 128, 0, stream>>>(stats, gamma, beta, 1.0f / (float)N);
        bngelu_k<<<(N * COUT / 4 + 255) / 256, 256, 0, stream>>>(out, stats, N * COUT / 4);
    }
}

// Round 15
// 380.838 us; speedup vs baseline: 1.1273x; 1.1273x over previous
//
#include <hip/hip_runtime.h>

typedef unsigned short u16;
typedef unsigned int u32;
typedef unsigned long long u64;
using f32x4 = __attribute__((ext_vector_type(4))) float;
using bf16x8 = __attribute__((ext_vector_type(8))) short;

#define CIN 128
#define COUT 128
#define BM 128
#define LDA 136  // padded LDS row stride for Asub in fallback kernel only

__device__ inline u16 bf16rn(float f) {
    union { float f; u32 u; } v; v.f = f;
    u32 u = v.u;
    u += 0x7FFFu + ((u >> 16) & 1u);   // round-to-nearest-even
    return (u16)(u >> 16);
}

// ---------------- fallback-path precasts (also used as prep_k bodies) ----------------
__global__ void precast_feats_k(const float* __restrict__ in, u16* __restrict__ out, int total8) {
    int i = blockIdx.x * blockDim.x + threadIdx.x;
    if (i >= total8) return;
    const float4* p = (const float4*)in + 2 * (size_t)i;
    float4 a = p[0], b = p[1];
    u32 o0 = (u32)bf16rn(a.x) | ((u32)bf16rn(a.y) << 16);
    u32 o1 = (u32)bf16rn(a.z) | ((u32)bf16rn(a.w) << 16);
    u32 o2 = (u32)bf16rn(b.x) | ((u32)bf16rn(b.y) << 16);
    u32 o3 = (u32)bf16rn(b.z) | ((u32)bf16rn(b.w) << 16);
    ((uint4*)out)[i] = make_uint4(o0, o1, o2, o3);
}

// Wt fragment-linear layout: Wt[k][frag][lane][e], frag = cn*4+kk (32 frags).
// Element = W[k][c][d], d = cn*16 + (lane&15), c = kk*32 + (lane>>4)*8 + e.
// LDS staging is a pure linear memcpy; inner ds_read_b128 at lane*16B is
// conflict-free (verified r11: SQ_LDS_BANK_CONFLICT 5.4M -> 0).
__global__ void precast_w_k(const float* __restrict__ W, u16* __restrict__ Wt, int total) {
    int i = blockIdx.x * blockDim.x + threadIdx.x;
    if (i >= total) return;
    int k = i >> 14;
    int rem = i & 16383;
    int f = rem >> 9;          // frag 0..31
    int l = (rem >> 3) & 63;   // lane
    int e = rem & 7;
    int cn = f >> 2, kk = f & 3;
    int d = cn * 16 + (l & 15);
    int c = kk * 32 + ((l >> 4) << 3) + e;
    Wt[i] = bf16rn(W[(k << 14) + (c << 7) + d]);
}

// ---------------- fused prep: precast feats || precast W || hist ----------------
__global__ void prep_k(const float* __restrict__ feats, const float* __restrict__ W,
                       const int* __restrict__ oi, const int* __restrict__ valid,
                       u16* __restrict__ fb, u16* __restrict__ Wt,
                       int* __restrict__ cnt, int* __restrict__ pos,
                       int* __restrict__ bc0, int* __restrict__ bc1,
                       int total8, int totalw, int N, int E, int b0, int b1) {
    const int blk = blockIdx.x;
    const int tid = threadIdx.x;
    if (blk < b0) {
        int i = blk * 256 + tid;
        if (i >= total8) return;
        const float4* p = (const float4*)feats + 2 * (size_t)i;
        float4 a = p[0], q = p[1];
        u32 o0 = (u32)bf16rn(a.x) | ((u32)bf16rn(a.y) << 16);
        u32 o1 = (u32)bf16rn(a.z) | ((u32)bf16rn(a.w) << 16);
        u32 o2 = (u32)bf16rn(q.x) | ((u32)bf16rn(q.y) << 16);
        u32 o3 = (u32)bf16rn(q.z) | ((u32)bf16rn(q.w) << 16);
        ((uint4*)fb)[i] = make_uint4(o0, o1, o2, o3);
    } else if (blk < b0 + b1) {
        int i = (blk - b0) * 256 + tid;
        if (i >= totalw) return;
        int k = i >> 14;
        int rem = i & 16383;
        int f = rem >> 9;
        int l = (rem >> 3) & 63;
        int e = rem & 7;
        int cn = f >> 2, kk = f & 3;
        int d = cn * 16 + (l & 15);
        int c = kk * 32 + ((l >> 4) << 3) + e;
        Wt[i] = bf16rn(W[(k << 14) + (c << 7) + d]);
    } else {
        const int b = blk - b0 - b1;            // local hist block index
        const int e = b * 256 + tid;
        const int k0 = (b * 256) / N;
        bool v = false; bool g = false;
        if (e < E) {
            v = valid[e] > 0;
            g = (e >= (k0 + 1) * N);
            if (v) pos[e] = atomicAdd(&cnt[oi[e]], 1);
        }
        const int lane = tid & 63, wid = tid >> 6;
        u64 m0 = __ballot(v && !g);
        u64 m1 = __ballot(v && g);
        __shared__ int wt[4][2];
        if (lane == 0) { wt[wid][0] = __popcll(m0); wt[wid][1] = __popcll(m1); }
        __syncthreads();
        if (tid == 0) bc0[b] = wt[0][0] + wt[1][0] + wt[2][0] + wt[3][0];
        if (tid == 1) bc1[b] = wt[0][1] + wt[1][1] + wt[2][1] + wt[3][1];
    }
}

// ---------------- fallback-path hist (unfused) ----------------
__global__ void hist_k(const int* __restrict__ oi, const int* __restrict__ valid,
                       int* __restrict__ cnt, int* __restrict__ pos,
                       int* __restrict__ bc0, int* __restrict__ bc1, int N, int E) {
    const int tid = threadIdx.x;
    const int b = blockIdx.x;
    const int e = b * 256 + tid;
    const int k0 = (b * 256) / N;
    bool v = false; bool g = false;
    if (e < E) {
        v = valid[e] > 0;
        g = (e >= (k0 + 1) * N);
        if (v) pos[e] = atomicAdd(&cnt[oi[e]], 1);
    }
    const int lane = tid & 63, wid = tid >> 6;
    u64 m0 = __ballot(v && !g);
    u64 m1 = __ballot(v && g);
    __shared__ int wt[4][2];
    if (lane == 0) { wt[wid][0] = __popcll(m0); wt[wid][1] = __popcll(m1); }
    __syncthreads();
    if (tid == 0) bc0[b] = wt[0][0] + wt[1][0] + wt[2][0] + wt[3][0];
    if (tid == 1) bc1[b] = wt[0][1] + wt[1][1] + wt[2][1] + wt[3][1];
}

// ---- hierarchical exclusive scan of cnt[N] -> offs[N+1] ----
__global__ void scan_sum_k(const int* __restrict__ cnt, int* __restrict__ bsum, int N) {
    __shared__ int red[256];
    int t = threadIdx.x;
    int i = blockIdx.x * 256 + t;
    red[t] = (i < N) ? cnt[i] : 0;
    __syncthreads();
    #pragma unroll
    for (int d = 128; d > 0; d >>= 1) {
        if (t < d) red[t] += red[t + d];
        __syncthreads();
    }
    if (t == 0) bsum[blockIdx.x] = red[0];
}

__global__ void scan_top_k(int* __restrict__ bsum, int nb) {
    __shared__ int part[1024];
    int t = threadIdx.x;
    int v = (t < nb) ? bsum[t] : 0;
    part[t] = v;
    __syncthreads();
    for (int d = 1; d < 1024; d <<= 1) {
        int x = (t >= d) ? part[t - d] : 0;
        __syncthreads();
        part[t] += x;
        __syncthreads();
    }
    if (t < nb) bsum[t] = part[t] - v;   // exclusive
}

// ---------------- fused scan_apply || kscan (block-range split) ----------------
__global__ void scan_apply_kscan_k(const int* __restrict__ cnt, const int* __restrict__ bsum,
                                   int* __restrict__ offs,
                                   const int* __restrict__ bc0, const int* __restrict__ bc1,
                                   int* __restrict__ base0, int* __restrict__ base1,
                                   int* __restrict__ kcount, int N, int nb) {
    const int t = threadIdx.x;
    __shared__ int part[256];
    if ((int)blockIdx.x < nb) {
        int i = blockIdx.x * 256 + t;
        int v = (i < N) ? cnt[i] : 0;
        part[t] = v;
        __syncthreads();
        #pragma unroll
        for (int d = 1; d < 256; d <<= 1) {
            int x = (t >= d) ? part[t - d] : 0;
            __syncthreads();
            part[t] += x;
            __syncthreads();
        }
        int base = bsum[blockIdx.x];
        if (i < N) {
            int excl = base + part[t] - v;
            offs[i] = excl;
            if (i == N - 1) offs[N] = excl + v;
        }
    } else {
        const int k = blockIdx.x - nb;
        const int blo = (k * N) / 256;
        const int bhi = ((k + 1) * N - 1) / 256;
        const int len = bhi - blo + 1;        // <= 256 (guarded host-side)
        const int b = blo + t;
        int k0b = 0, contrib = 0;
        const bool inr = (t < len);
        if (inr) {
            k0b = (b * 256) / N;
            contrib = (k0b == k) ? bc0[b] : bc1[b];
        }
        part[t] = contrib;
        __syncthreads();
        #pragma unroll
        for (int d = 1; d < 256; d <<= 1) {
            int x = (t >= d) ? part[t - d] : 0;
            __syncthreads();
            part[t] += x;
            __syncthreads();
        }
        if (inr) {
            int excl = part[t] - contrib;
            if (k0b == k) base0[b] = excl; else base1[b] = excl;
            if (t == len - 1) kcount[k] = part[t];
        }
    }
}

// ---------------- rank: fully atomic-free ----------------
__global__ void rank_k(const int* __restrict__ oi, const int* __restrict__ ini,
                       const int* __restrict__ valid, const int* __restrict__ pos,
                       const int* __restrict__ offs,
                       const int* __restrict__ base0, const int* __restrict__ base1,
                       int* __restrict__ cin_arr, int* __restrict__ cpos_arr,
                       int N, int E, int cap) {
    const int tid = threadIdx.x;
    const int b = blockIdx.x;
    const int e = b * 256 + tid;
    const int k0 = (b * 256) / N;
    bool v = false; int k = 0, n = 0, ii = 0, p = 0;
    if (e < E) {
        v = valid[e] > 0;
        k = (e >= (k0 + 1) * N) ? k0 + 1 : k0;
        if (v) { n = oi[e]; ii = ini[e]; p = pos[e]; }
    }
    const int g = k - k0;   // 0 or 1
    const int lane = tid & 63, wid = tid >> 6;
    u64 m0 = __ballot(v && g == 0);
    u64 m1 = __ballot(v && g == 1);
    u64 lt = (1ull << lane) - 1ull;
    int r0 = __popcll(m0 & lt);
    int r1 = __popcll(m1 & lt);
    __shared__ int wt[4][2];
    if (lane == 0) { wt[wid][0] = __popcll(m0); wt[wid][1] = __popcll(m1); }
    __syncthreads();
    if (v) {
        int wbase = 0;
        #pragma unroll
        for (int w2 = 0; w2 < 4; ++w2) if (w2 < wid) wbase += wt[w2][g];
        int kb = g ? base1[b] : base0[b];
        int slot = kb + wbase + (g ? r1 : r0);
        int pg = offs[n] + p;
        cin_arr[k * N + slot] = ii;
        cpos_arr[k * N + slot] = (pg < cap) ? pg : (cap + n);
    }
}

// ---------------- phase A: persistent-per-k gather + GEMM + sorted store ----------------
// Grid = nbk x K. Each block stages W[k] ONCE, then its 8 waves grid-stride
// over 16-row chunks (gather -> compute -> store per chunk; latency hidden
// across the 16 resident waves as in r13). NO prefetch double-buffer: r14's
// an[]/a0[] loop-carried buffers spilled to scratch (FETCH 61->617 MB) and
// invalidated the experiment. Register footprint here is byte-identical to
// the r13 body (a0[4]=16 VGPR + acc=32 AGPR).
// msg row layout: word w = 4*l15 + q holds packed bf16 cols (l15+32q, l15+32q+16)
__launch_bounds__(512, 6)
__global__ void convA_k(const u16* __restrict__ fb, const u16* __restrict__ Wt,
                        const int* __restrict__ cin_arr, const int* __restrict__ cpos_arr,
                        const int* __restrict__ kcount, u32* __restrict__ msg,
                        float* __restrict__ out, int N, int cap, int nbk)
{
    const int k = blockIdx.y;
    const int kc = kcount[k];

    __shared__ __align__(16) u16 Bsub[COUT * CIN];   // 32 KB, fragment-linear

    const int tid = threadIdx.x;
    const int wave = tid >> 6, lane = tid & 63;
    const int l15 = lane & 15, l4 = lane >> 4;
    const int base = k * N;

    // stage W[k] (fragment-order, 32 KB) into LDS: pure linear memcpy
    {
        const u16* wk = Wt + ((size_t)k << 14);
        #pragma unroll
        for (int j = 0; j < 4; ++j)
            *(uint4*)(Bsub + j * 4096 + tid * 8) = *(const uint4*)(wk + j * 4096 + tid * 8);
    }
    __syncthreads();

    const int nch = (kc + 15) >> 4;          // 16-row chunks for this k
    const int wstep = nbk * 8;               // total waves servicing this k

    for (int c = blockIdx.x * 8 + wave; c < nch; c += wstep) {
        // gather chunk: 16 random rows -> regs, MFMA layout
        int r0 = c * 16 + l15;
        int i0 = cin_arr[base + min(r0, kc - 1)];
        if (r0 >= kc) i0 = 0;   // read valid memory; rows discarded below
        const u16* pa = fb + (size_t)i0 * CIN + l4 * 8;
        bf16x8 a0[4];
        #pragma unroll
        for (int kk = 0; kk < 4; ++kk)
            a0[kk] = *(const bf16x8*)(pa + kk * 32);

        // compute: 16 rows x 128 cols
        f32x4 acc[8];
        #pragma unroll
        for (int y = 0; y < 8; ++y)
            acc[y] = (f32x4){0.f, 0.f, 0.f, 0.f};
        #pragma unroll
        for (int kk = 0; kk < 4; ++kk) {
            #pragma unroll
            for (int cn = 0; cn < 8; ++cn) {
                bf16x8 b = *(const bf16x8*)(Bsub + (((cn << 2) + kk) << 9) + lane * 8);
                acc[cn] = __builtin_amdgcn_mfma_f32_16x16x32_bf16(a0[kk], b, acc[cn], 0, 0, 0);
            }
        }

        // epilogue: sorted msg store (or atomic fallback)
        #pragma unroll
        for (int j = 0; j < 4; ++j) {
            int rl = c * 16 + l4 * 4 + j;
            if (rl >= kc) continue;
            int v = cpos_arr[base + rl];   // 16 lanes share each addr -> broadcast
            if (v < cap) {
                u32 w0 = (u32)bf16rn(acc[0][j]) | ((u32)bf16rn(acc[1][j]) << 16);
                u32 w1 = (u32)bf16rn(acc[2][j]) | ((u32)bf16rn(acc[3][j]) << 16);
                u32 w2 = (u32)bf16rn(acc[4][j]) | ((u32)bf16rn(acc[5][j]) << 16);
                u32 w3 = (u32)bf16rn(acc[6][j]) | ((u32)bf16rn(acc[7][j]) << 16);
                *(uint4*)(msg + (size_t)v * 64 + 4 * l15) = make_uint4(w0, w1, w2, w3);
            } else {
                int n = v - cap;
                float* dst = out + (size_t)n * COUT + l15;
                #pragma unroll
                for (int cn = 0; cn < 8; ++cn)
                    atomicAdd(dst + cn * 16, acc[cn][j]);
            }
        }
    }
}

// ---------------- phase B (wmode=1): uint4 segment-sum + fused stats ----------------
__global__ void convB_stats_k(const u32* __restrict__ msg, const int* __restrict__ offs,
                              float* __restrict__ out, float* __restrict__ stats,
                              int N, int cap, int nblk)
{
    const int tid = threadIdx.x;
    const int wave = tid >> 6, lane = tid & 63;
    const int sub = lane >> 4, l15 = lane & 15;
    const int colA = l15 + 32 * sub;
    float sA = 0.f, qA = 0.f, sB = 0.f, qB = 0.f;

    for (int n = blockIdx.x * 4 + wave; n < N; n += nblk * 4) {
        int s = min(offs[n], cap), e = min(offs[n + 1], cap);
        float a0 = 0.f, a1 = 0.f, a2 = 0.f, a3 = 0.f;
        float b0 = 0.f, b1 = 0.f, b2 = 0.f, b3 = 0.f;
        for (int r = s; r < e; r += 4) {
            int ent = r + sub;
            uint4 v = make_uint4(0u, 0u, 0u, 0u);
            if (ent < e) v = *(const uint4*)(msg + (size_t)ent * 64 + 4 * l15);
            a0 += __uint_as_float(v.x << 16); b0 += __uint_as_float(v.x & 0xFFFF0000u);
            a1 += __uint_as_float(v.y << 16); b1 += __uint_as_float(v.y & 0xFFFF0000u);
            a2 += __uint_as_float(v.z << 16); b2 += __uint_as_float(v.z & 0xFFFF0000u);
            a3 += __uint_as_float(v.w << 16); b3 += __uint_as_float(v.w & 0xFFFF0000u);
        }
        #define RED4(x) { x += __shfl_xor(x, 16, 64); x += __shfl_xor(x, 32, 64); }
        RED4(a0) RED4(a1) RED4(a2) RED4(a3)
        RED4(b0) RED4(b1) RED4(b2) RED4(b3)
        #undef RED4
        float va = (sub == 0) ? a0 : (sub == 1) ? a1 : (sub == 2) ? a2 : a3;
        float vb = (sub == 0) ? b0 : (sub == 1) ? b1 : (sub == 2) ? b2 : b3;
        float* po = out + (size_t)n * COUT;
        po[colA]      = va;
        po[colA + 16] = vb;
        sA += va; qA += va * va;
        sB += vb; qB += vb * vb;
    }

    __shared__ float st[4][64][4];
    st[wave][lane][0] = sA; st[wave][lane][1] = qA;
    st[wave][lane][2] = sB; st[wave][lane][3] = qB;
    __syncthreads();
    int lane2 = tid >> 2, slot = tid & 3;
    float sum = st[0][lane2][slot] + st[1][lane2][slot]
              + st[2][lane2][slot] + st[3][lane2][slot];
    int colb = (lane2 & 15) + 32 * (lane2 >> 4) + ((slot >= 2) ? 16 : 0);
    atomicAdd(&stats[((slot & 1) ? 128 : 0) + colb], sum);
}

// ---------------- phase B (wmode=0): += segment-sum (composes with atomics) ----
__global__ void convB_k(const u32* __restrict__ msg, const int* __restrict__ offs,
                        float* __restrict__ out, int N, int cap)
{
    int wave = threadIdx.x >> 6, lane = threadIdx.x & 63;
    int n = blockIdx.x * 4 + wave;
    if (n >= N) return;
    int s = min(offs[n], cap), e = min(offs[n + 1], cap);
    float a0 = 0.f, a1 = 0.f;
    int r = s;
    for (; r + 2 <= e; r += 2) {
        u32 v0 = msg[(size_t)r * 64 + lane];
        u32 v1 = msg[(size_t)(r + 1) * 64 + lane];
        a0 += __uint_as_float(v0 << 16) + __uint_as_float(v1 << 16);
        a1 += __uint_as_float(v0 & 0xFFFF0000u) + __uint_as_float(v1 & 0xFFFF0000u);
    }
    if (r < e) {
        u32 v0 = msg[(size_t)r * 64 + lane];
        a0 += __uint_as_float(v0 << 16);
        a1 += __uint_as_float(v0 & 0xFFFF0000u);
    }
    int c0 = (lane >> 2) + ((lane & 3) << 5);
    float* po = out + (size_t)n * COUT;
    po[c0]      += a0;
    po[c0 + 16] += a1;
}

// ---------------- fallback atomic conv (frag-linear Wt) ----------------
__launch_bounds__(256, 2)
__global__ void conv_k(const u16* __restrict__ fb, const u16* __restrict__ Wt,
                       const int* __restrict__ in_idx, const int* __restrict__ out_idx,
                       const int* __restrict__ valid, float* __restrict__ out, int N)
{
    __shared__ __align__(16) u16 Asub[BM * LDA];
    __shared__ __align__(16) u16 Bsub[COUT * CIN];   // fragment-linear
    __shared__ int orow[BM];

    const int tile = blockIdx.x;
    const int k = blockIdx.y;
    const int tid = threadIdx.x;
    const int m0 = tile * BM;

    {
        const u16* wk = Wt + ((size_t)k << 14);
        #pragma unroll
        for (int j = 0; j < 8; ++j)
            *(uint4*)(Bsub + j * 2048 + tid * 8) = *(const uint4*)(wk + j * 2048 + tid * 8);
    }
    {
        int r = tid >> 1, half = tid & 1;
        int m = m0 + r;
        int act = 0, ii = 0, oi = -1;
        if (m < N) {
            int base = k * N + m;
            act = valid[base];
            ii  = in_idx[base];
            oi  = out_idx[base];
        }
        if (half == 0) orow[r] = (m < N && act > 0) ? oi : -1;
        if (m < N && act > 0) {
            const u16* src = fb + (size_t)ii * CIN + half * 64;
            u16* dst = Asub + r * LDA + half * 64;
            #pragma unroll
            for (int j = 0; j < 8; ++j)
                *(uint4*)(dst + j * 8) = *(const uint4*)(src + j * 8);
        }
    }
    __syncthreads();

    const int wave = tid >> 6, lane = tid & 63;
    const int l15 = lane & 15, l4 = lane >> 4;

    f32x4 acc[2][8];
    #pragma unroll
    for (int x = 0; x < 2; ++x)
        #pragma unroll
        for (int y = 0; y < 8; ++y)
            acc[x][y] = (f32x4){0.f, 0.f, 0.f, 0.f};

    #pragma unroll
    for (int kk = 0; kk < 4; ++kk) {
        const int coff = kk * 32 + l4 * 8;
        bf16x8 a0 = *(const bf16x8*)(Asub + (wave * 32 + l15) * LDA + coff);
        bf16x8 a1 = *(const bf16x8*)(Asub + (wave * 32 + 16 + l15) * LDA + coff);
        #pragma unroll
        for (int cn = 0; cn < 8; ++cn) {
            bf16x8 b = *(const bf16x8*)(Bsub + (((cn << 2) + kk) << 9) + lane * 8);
            acc[0][cn] = __builtin_amdgcn_mfma_f32_16x16x32_bf16(a0, b, acc[0][cn], 0, 0, 0);
            acc[1][cn] = __builtin_amdgcn_mfma_f32_16x16x32_bf16(a1, b, acc[1][cn], 0, 0, 0);
        }
    }

    #pragma unroll
    for (int rm = 0; rm < 2; ++rm) {
        #pragma unroll
        for (int j = 0; j < 4; ++j) {
            int rl = wave * 32 + rm * 16 + l4 * 4 + j;
            int od = orow[rl];
            if (od >= 0) {
                float* dst = out + (size_t)od * COUT + l15;
                #pragma unroll
                for (int cn = 0; cn < 8; ++cn)
                    atomicAdd(dst + cn * 16, acc[rm][cn][j]);
            }
        }
    }
}

// ---------------- stats / BN+GELU ----------------
__global__ void stats_k(const float* __restrict__ out, float* __restrict__ stats, int N) {
    const int tid = threadIdx.x;
    const int col = tid & 127;
    const int pr = tid >> 7;
    float s = 0.f, sq = 0.f;
    for (int r = blockIdx.x * 2 + pr; r < N; r += gridDim.x * 2) {
        float v = out[(size_t)r * COUT + col];
        s += v; sq += v * v;
    }
    __shared__ float red[512];
    red[tid] = s;
    red[256 + tid] = sq;
    __syncthreads();
    if (tid < 128) {
        atomicAdd(&stats[col],       red[tid] + red[tid + 128]);
        atomicAdd(&stats[128 + col], red[256 + tid] + red[384 + tid]);
    }
}

__global__ void finalize_k(float* __restrict__ stats, const float* __restrict__ gamma,
                           const float* __restrict__ beta, float invN) {
    int c = threadIdx.x;   // 128 threads
    float mean = stats[c] * invN;
    float var = stats[128 + c] * invN - mean * mean;
    float sc = rsqrtf(var + 1e-5f) * gamma[c];
    stats[256 + c] = sc;
    stats[384 + c] = beta[c] - mean * sc;
}

__global__ void bngelu_k(float* __restrict__ out, const float* __restrict__ stats, int total4) {
    int i = blockIdx.x * blockDim.x + threadIdx.x;
    if (i >= total4) return;
    float4 v = ((const float4*)out)[i];
    int cb = (i << 2) & 127;
    float r[4] = {v.x, v.y, v.z, v.w};
    #pragma unroll
    for (int e = 0; e < 4; ++e) {
        int c = cb + e;
        float y = r[e] * stats[256 + c] + stats[384 + c];
        r[e] = 0.5f * y * (1.0f + erff(y * 0.70710678118f));
    }
    ((float4*)out)[i] = make_float4(r[0], r[1], r[2], r[3]);
}

extern "C" void kernel_launch(void* const* d_in, const int* in_sizes, int n_in,
                              void* d_out, int out_size, void* d_ws, size_t ws_size,
                              hipStream_t stream) {
    const float* feats  = (const float*)d_in[0];
    const float* W      = (const float*)d_in[1];
    const float* gamma  = (const float*)d_in[2];
    const float* beta   = (const float*)d_in[3];
    const int*   in_idx = (const int*)d_in[4];
    const int*   outidx = (const int*)d_in[5];
    const int*   valid  = (const int*)d_in[6];
    const int N = in_sizes[0] / CIN;          // 40000
    const int K = in_sizes[1] / (CIN * COUT); // 27
    const int E = K * N;
    float* out = (float*)d_out;

    const int nb  = (N + 255) / 256;          // scan blocks (157) — must be <= 1024
    const int nbE = (E + 255) / 256;          // entry blocks (4219)

    const size_t fbB   = ((size_t)N * CIN * 2 + 255) & ~255ull;
    const size_t WtB   = ((size_t)K * CIN * COUT * 2 + 255) & ~255ull;
    const size_t cinB  = ((size_t)E * 4 + 255) & ~255ull;
    const size_t cposB = cinB;
    const size_t posB  = cinB;                                   // pos[E]
    const size_t cntB  = ((size_t)N * 4 + 255) & ~255ull;       // cnt[N]
    const size_t kcB   = 256;                                    // kcount[K]
    const size_t stB   = 2048;                                   // stats[512]
    const size_t offsB = ((size_t)(N + 1) * 4 + 255) & ~255ull;
    const size_t bsB   = ((size_t)nb * 4 + 255) & ~255ull;       // block sums
    const size_t nbEB  = ((size_t)nbE * 4 + 255) & ~255ull;      // bc0/bc1/base0/base1
    const size_t fixedB = fbB + WtB + cinB + cposB + posB + cntB + kcB + stB + offsB
                        + bsB + 4 * nbEB + 1024;

    int total8 = N * CIN / 8;
    int totalw = K * CIN * COUT;

    if (ws_size >= fixedB + (size_t)1024 * 256 && nb <= 1024 && nb + 1 <= 256) {
        long long capL = ((long long)ws_size - (long long)fixedB) / 256;
        if (capL > (long long)E) capL = E;
        const int cap = (int)capL;
        const int wmode = (cap >= E) ? 1 : 0;   // no overflow atomics possible

        char* w = (char*)d_ws;
        u32* msg      = (u32*)w;  w += (size_t)cap * 256;
        u16* fb       = (u16*)w;  w += fbB;
        u16* Wt       = (u16*)w;  w += WtB;
        int* cin_arr  = (int*)w;  w += cinB;
        int* cpos_arr = (int*)w;  w += cposB;
        int* pos      = (int*)w;  w += posB;
        int* cnt      = (int*)w;  w += cntB;   // cnt | kcount | stats contiguous
        int* kcount   = (int*)w;  w += kcB;
        float* stats  = (float*)w; w += stB;
        int* offs     = (int*)w;  w += offsB;
        int* bsum     = (int*)w;  w += bsB;
        int* bc0      = (int*)w;  w += nbEB;
        int* bc1      = (int*)w;  w += nbEB;
        int* base0    = (int*)w;  w += nbEB;
        int* base1    = (int*)w;

        if (!wmode)
            hipMemsetAsync(out, 0, (size_t)N * COUT * sizeof(float), stream);
        hipMemsetAsync(cnt, 0, cntB + kcB + stB, stream);

        const int b0 = (total8 + 255) / 256;
        const int b1 = (totalw + 255) / 256;
        prep_k<<<b0 + b1 + nbE, 256, 0, stream>>>(feats, W, outidx, valid, fb, Wt,
                                                  cnt, pos, bc0, bc1,
                                                  total8, totalw, N, E, b0, b1);
        scan_sum_k<<<nb, 256, 0, stream>>>(cnt, bsum, N);
        scan_top_k<<<1, 1024, 0, stream>>>(bsum, nb);
        scan_apply_kscan_k<<<nb + K, 256, 0, stream>>>(cnt, bsum, offs, bc0, bc1,
                                                       base0, base1, kcount, N, nb);
        rank_k<<<nbE, 256, 0, stream>>>(outidx, in_idx, valid, pos, offs,
                                        base0, base1, cin_arr, cpos_arr, N, E, cap);

        const int nbk = 24;   // persistent blocks per k (648 total ~ 2.5/CU)
        dim3 gA(nbk, K);
        convA_k<<<gA, 512, 0, stream>>>(fb, Wt, cin_arr, cpos_arr, kcount, msg, out,
                                        N, cap, nbk);

        if (wmode) {
            const int nblk = 2048;
            convB_stats_k<<<nblk, 256, 0, stream>>>(msg, offs, out, stats, N, cap, nblk);
        } else {
            convB_k<<<(N + 3) / 4, 256, 0, stream>>>(msg, offs, out, N, cap);
            stats_k<<<256, 256, 0, stream>>>(out, stats, N);
        }

        finalize_k<<<1, 128, 0, stream>>>(stats, gamma, beta, 1.0f / (float)N);
        bngelu_k<<<(N * COUT / 4 + 255) / 256, 256, 0, stream>>>(out, stats, N * COUT / 4);
    } else {
        // minimal-ws fallback: atomic path (~11.4 MB)
        u16* fb = (u16*)d_ws;
        u16* Wt = fb + (size_t)N * CIN;
        float* stats = (float*)(Wt + (size_t)K * CIN * COUT);

        hipMemsetAsync(out, 0, (size_t)N * COUT * sizeof(float), stream);
        hipMemsetAsync(stats, 0, 256 * sizeof(float), stream);

        precast_feats_k<<<(total8 + 255) / 256, 256, 0, stream>>>(feats, fb, total8);
        precast_w_k<<<(totalw + 255) / 256, 256, 0, stream>>>(W, Wt, totalw);

        dim3 g((N + BM - 1) / BM, K);
        conv_k<<<g, 256, 0, stream>>>(fb, Wt, in_idx, outidx, valid, out, N);

        stats_k<<<256, 256, 0, stream>>>(out, stats, N);
        finalize_k<<<1, 128, 0, stream>>>(stats, gamma, beta, 1.0f / (float)N);
        bngelu_k<<<(N * COUT / 4 + 255) / 256, 256, 0, stream>>>(out, stats, N * COUT / 4);
    }
}

// Round 16
// 175.697 us; speedup vs baseline: 2.4436x; 2.1676x over previous
//
#include <hip/hip_runtime.h>

typedef unsigned short u16;
typedef unsigned int u32;
typedef unsigned long long u64;
using f32x4 = __attribute__((ext_vector_type(4))) float;
using bf16x8 = __attribute__((ext_vector_type(8))) short;

#define CIN 128
#define COUT 128
#define BM 128
#define LDA 136  // padded LDS row stride for Asub in fallback kernel only

__device__ inline u16 bf16rn(float f) {
    union { float f; u32 u; } v; v.f = f;
    u32 u = v.u;
    u += 0x7FFFu + ((u >> 16) & 1u);   // round-to-nearest-even
    return (u16)(u >> 16);
}

// ---------------- fallback-path precasts (also used as prep_k bodies) ----------------
__global__ void precast_feats_k(const float* __restrict__ in, u16* __restrict__ out, int total8) {
    int i = blockIdx.x * blockDim.x + threadIdx.x;
    if (i >= total8) return;
    const float4* p = (const float4*)in + 2 * (size_t)i;
    float4 a = p[0], b = p[1];
    u32 o0 = (u32)bf16rn(a.x) | ((u32)bf16rn(a.y) << 16);
    u32 o1 = (u32)bf16rn(a.z) | ((u32)bf16rn(a.w) << 16);
    u32 o2 = (u32)bf16rn(b.x) | ((u32)bf16rn(b.y) << 16);
    u32 o3 = (u32)bf16rn(b.z) | ((u32)bf16rn(b.w) << 16);
    ((uint4*)out)[i] = make_uint4(o0, o1, o2, o3);
}

// Wt fragment-linear layout: Wt[k][frag][lane][e], frag = cn*4+kk (32 frags).
// Element = W[k][c][d], d = cn*16 + (lane&15), c = kk*32 + (lane>>4)*8 + e.
// LDS staging is a pure linear memcpy; inner ds_read_b128 at lane*16B is
// conflict-free (verified r11: SQ_LDS_BANK_CONFLICT 5.4M -> 0).
__global__ void precast_w_k(const float* __restrict__ W, u16* __restrict__ Wt, int total) {
    int i = blockIdx.x * blockDim.x + threadIdx.x;
    if (i >= total) return;
    int k = i >> 14;
    int rem = i & 16383;
    int f = rem >> 9;          // frag 0..31
    int l = (rem >> 3) & 63;   // lane
    int e = rem & 7;
    int cn = f >> 2, kk = f & 3;
    int d = cn * 16 + (l & 15);
    int c = kk * 32 + ((l >> 4) << 3) + e;
    Wt[i] = bf16rn(W[(k << 14) + (c << 7) + d]);
}

// ---------------- fused prep: precast feats || precast W || hist ----------------
__global__ void prep_k(const float* __restrict__ feats, const float* __restrict__ W,
                       const int* __restrict__ oi, const int* __restrict__ valid,
                       u16* __restrict__ fb, u16* __restrict__ Wt,
                       int* __restrict__ cnt, int* __restrict__ pos,
                       int* __restrict__ bc0, int* __restrict__ bc1,
                       int total8, int totalw, int N, int E, int b0, int b1) {
    const int blk = blockIdx.x;
    const int tid = threadIdx.x;
    if (blk < b0) {
        int i = blk * 256 + tid;
        if (i >= total8) return;
        const float4* p = (const float4*)feats + 2 * (size_t)i;
        float4 a = p[0], q = p[1];
        u32 o0 = (u32)bf16rn(a.x) | ((u32)bf16rn(a.y) << 16);
        u32 o1 = (u32)bf16rn(a.z) | ((u32)bf16rn(a.w) << 16);
        u32 o2 = (u32)bf16rn(q.x) | ((u32)bf16rn(q.y) << 16);
        u32 o3 = (u32)bf16rn(q.z) | ((u32)bf16rn(q.w) << 16);
        ((uint4*)fb)[i] = make_uint4(o0, o1, o2, o3);
    } else if (blk < b0 + b1) {
        int i = (blk - b0) * 256 + tid;
        if (i >= totalw) return;
        int k = i >> 14;
        int rem = i & 16383;
        int f = rem >> 9;
        int l = (rem >> 3) & 63;
        int e = rem & 7;
        int cn = f >> 2, kk = f & 3;
        int d = cn * 16 + (l & 15);
        int c = kk * 32 + ((l >> 4) << 3) + e;
        Wt[i] = bf16rn(W[(k << 14) + (c << 7) + d]);
    } else {
        const int b = blk - b0 - b1;            // local hist block index
        const int e = b * 256 + tid;
        const int k0 = (b * 256) / N;
        bool v = false; bool g = false;
        if (e < E) {
            v = valid[e] > 0;
            g = (e >= (k0 + 1) * N);
            if (v) pos[e] = atomicAdd(&cnt[oi[e]], 1);
        }
        const int lane = tid & 63, wid = tid >> 6;
        u64 m0 = __ballot(v && !g);
        u64 m1 = __ballot(v && g);
        __shared__ int wt[4][2];
        if (lane == 0) { wt[wid][0] = __popcll(m0); wt[wid][1] = __popcll(m1); }
        __syncthreads();
        if (tid == 0) bc0[b] = wt[0][0] + wt[1][0] + wt[2][0] + wt[3][0];
        if (tid == 1) bc1[b] = wt[0][1] + wt[1][1] + wt[2][1] + wt[3][1];
    }
}

// ---------------- fallback-path hist (unfused) ----------------
__global__ void hist_k(const int* __restrict__ oi, const int* __restrict__ valid,
                       int* __restrict__ cnt, int* __restrict__ pos,
                       int* __restrict__ bc0, int* __restrict__ bc1, int N, int E) {
    const int tid = threadIdx.x;
    const int b = blockIdx.x;
    const int e = b * 256 + tid;
    const int k0 = (b * 256) / N;
    bool v = false; bool g = false;
    if (e < E) {
        v = valid[e] > 0;
        g = (e >= (k0 + 1) * N);
        if (v) pos[e] = atomicAdd(&cnt[oi[e]], 1);
    }
    const int lane = tid & 63, wid = tid >> 6;
    u64 m0 = __ballot(v && !g);
    u64 m1 = __ballot(v && g);
    __shared__ int wt[4][2];
    if (lane == 0) { wt[wid][0] = __popcll(m0); wt[wid][1] = __popcll(m1); }
    __syncthreads();
    if (tid == 0) bc0[b] = wt[0][0] + wt[1][0] + wt[2][0] + wt[3][0];
    if (tid == 1) bc1[b] = wt[0][1] + wt[1][1] + wt[2][1] + wt[3][1];
}

// ---- hierarchical exclusive scan of cnt[N] -> offs[N+1] ----
__global__ void scan_sum_k(const int* __restrict__ cnt, int* __restrict__ bsum, int N) {
    __shared__ int red[256];
    int t = threadIdx.x;
    int i = blockIdx.x * 256 + t;
    red[t] = (i < N) ? cnt[i] : 0;
    __syncthreads();
    #pragma unroll
    for (int d = 128; d > 0; d >>= 1) {
        if (t < d) red[t] += red[t + d];
        __syncthreads();
    }
    if (t == 0) bsum[blockIdx.x] = red[0];
}

__global__ void scan_top_k(int* __restrict__ bsum, int nb) {
    __shared__ int part[1024];
    int t = threadIdx.x;
    int v = (t < nb) ? bsum[t] : 0;
    part[t] = v;
    __syncthreads();
    for (int d = 1; d < 1024; d <<= 1) {
        int x = (t >= d) ? part[t - d] : 0;
        __syncthreads();
        part[t] += x;
        __syncthreads();
    }
    if (t < nb) bsum[t] = part[t] - v;   // exclusive
}

// ---------------- fused scan_apply || kscan (block-range split) ----------------
__global__ void scan_apply_kscan_k(const int* __restrict__ cnt, const int* __restrict__ bsum,
                                   int* __restrict__ offs,
                                   const int* __restrict__ bc0, const int* __restrict__ bc1,
                                   int* __restrict__ base0, int* __restrict__ base1,
                                   int* __restrict__ kcount, int N, int nb) {
    const int t = threadIdx.x;
    __shared__ int part[256];
    if ((int)blockIdx.x < nb) {
        int i = blockIdx.x * 256 + t;
        int v = (i < N) ? cnt[i] : 0;
        part[t] = v;
        __syncthreads();
        #pragma unroll
        for (int d = 1; d < 256; d <<= 1) {
            int x = (t >= d) ? part[t - d] : 0;
            __syncthreads();
            part[t] += x;
            __syncthreads();
        }
        int base = bsum[blockIdx.x];
        if (i < N) {
            int excl = base + part[t] - v;
            offs[i] = excl;
            if (i == N - 1) offs[N] = excl + v;
        }
    } else {
        const int k = blockIdx.x - nb;
        const int blo = (k * N) / 256;
        const int bhi = ((k + 1) * N - 1) / 256;
        const int len = bhi - blo + 1;        // <= 256 (guarded host-side)
        const int b = blo + t;
        int k0b = 0, contrib = 0;
        const bool inr = (t < len);
        if (inr) {
            k0b = (b * 256) / N;
            contrib = (k0b == k) ? bc0[b] : bc1[b];
        }
        part[t] = contrib;
        __syncthreads();
        #pragma unroll
        for (int d = 1; d < 256; d <<= 1) {
            int x = (t >= d) ? part[t - d] : 0;
            __syncthreads();
            part[t] += x;
            __syncthreads();
        }
        if (inr) {
            int excl = part[t] - contrib;
            if (k0b == k) base0[b] = excl; else base1[b] = excl;
            if (t == len - 1) kcount[k] = part[t];
        }
    }
}

// ---------------- rank: fully atomic-free ----------------
__global__ void rank_k(const int* __restrict__ oi, const int* __restrict__ ini,
                       const int* __restrict__ valid, const int* __restrict__ pos,
                       const int* __restrict__ offs,
                       const int* __restrict__ base0, const int* __restrict__ base1,
                       int* __restrict__ cin_arr, int* __restrict__ cpos_arr,
                       int N, int E, int cap) {
    const int tid = threadIdx.x;
    const int b = blockIdx.x;
    const int e = b * 256 + tid;
    const int k0 = (b * 256) / N;
    bool v = false; int k = 0, n = 0, ii = 0, p = 0;
    if (e < E) {
        v = valid[e] > 0;
        k = (e >= (k0 + 1) * N) ? k0 + 1 : k0;
        if (v) { n = oi[e]; ii = ini[e]; p = pos[e]; }
    }
    const int g = k - k0;   // 0 or 1
    const int lane = tid & 63, wid = tid >> 6;
    u64 m0 = __ballot(v && g == 0);
    u64 m1 = __ballot(v && g == 1);
    u64 lt = (1ull << lane) - 1ull;
    int r0 = __popcll(m0 & lt);
    int r1 = __popcll(m1 & lt);
    __shared__ int wt[4][2];
    if (lane == 0) { wt[wid][0] = __popcll(m0); wt[wid][1] = __popcll(m1); }
    __syncthreads();
    if (v) {
        int wbase = 0;
        #pragma unroll
        for (int w2 = 0; w2 < 4; ++w2) if (w2 < wid) wbase += wt[w2][g];
        int kb = g ? base1[b] : base0[b];
        int slot = kb + wbase + (g ? r1 : r0);
        int pg = offs[n] + p;
        cin_arr[k * N + slot] = ii;
        cpos_arr[k * N + slot] = (pg < cap) ? pg : (cap + n);
    }
}

// ---------------- phase A: gather + GEMM + sorted store (r13 verified best) ----------------
// 512 threads, 8 waves, 16 rows/wave, one 128-row tile per block (NO
// persistent loop: r14/r15 loop-carried variants spilled a0/acc to scratch —
// FETCH 61->600+ MB — and regressed 2.5x; this exact body measured 47 us,
// FETCH 61 MB, VGPR 32, 0 bank conflicts). B staged via linear memcpy of
// fragment-order Wt; A gathered into registers in MFMA layout before staging;
// cpos read post-MFMA.
// msg row layout: word w = 4*l15 + q holds packed bf16 cols (l15+32q, l15+32q+16)
__launch_bounds__(512, 6)
__global__ void convA_k(const u16* __restrict__ fb, const u16* __restrict__ Wt,
                        const int* __restrict__ cin_arr, const int* __restrict__ cpos_arr,
                        const int* __restrict__ kcount, u32* __restrict__ msg,
                        float* __restrict__ out, int N, int cap)
{
    const int k = blockIdx.y;
    const int kc = kcount[k];
    const int m0 = blockIdx.x * BM;
    if (m0 >= kc) return;

    __shared__ __align__(16) u16 Bsub[COUT * CIN];   // 32 KB, fragment-linear

    const int tid = threadIdx.x;
    const int wave = tid >> 6, lane = tid & 63;
    const int l15 = lane & 15, l4 = lane >> 4;
    const int base = k * N;

    // A fragments: global -> regs, MFMA layout. One 16-row set per wave.
    int r0 = m0 + wave * 16 + l15;
    int i0 = cin_arr[base + min(r0, kc - 1)];
    if (r0 >= kc) i0 = 0;   // read valid memory; result rows are discarded
    const u16* pa0 = fb + (size_t)i0 * CIN + l4 * 8;
    bf16x8 a0[4];
    #pragma unroll
    for (int kk = 0; kk < 4; ++kk)
        a0[kk] = *(const bf16x8*)(pa0 + kk * 32);

    // stage W[k] (fragment-order, 32 KB) into LDS: pure linear memcpy
    {
        const u16* wk = Wt + ((size_t)k << 14);
        #pragma unroll
        for (int j = 0; j < 4; ++j)
            *(uint4*)(Bsub + j * 4096 + tid * 8) = *(const uint4*)(wk + j * 4096 + tid * 8);
    }
    __syncthreads();

    f32x4 acc[8];
    #pragma unroll
    for (int y = 0; y < 8; ++y)
        acc[y] = (f32x4){0.f, 0.f, 0.f, 0.f};

    #pragma unroll
    for (int kk = 0; kk < 4; ++kk) {
        #pragma unroll
        for (int cn = 0; cn < 8; ++cn) {
            bf16x8 b = *(const bf16x8*)(Bsub + (((cn << 2) + kk) << 9) + lane * 8);
            acc[cn] = __builtin_amdgcn_mfma_f32_16x16x32_bf16(a0[kk], b, acc[cn], 0, 0, 0);
        }
    }

    #pragma unroll
    for (int j = 0; j < 4; ++j) {
        int rl = m0 + wave * 16 + l4 * 4 + j;
        if (rl >= kc) continue;
        int v = cpos_arr[base + rl];   // 16 lanes share each addr -> broadcast
        if (v < cap) {
            u32 w0 = (u32)bf16rn(acc[0][j]) | ((u32)bf16rn(acc[1][j]) << 16);
            u32 w1 = (u32)bf16rn(acc[2][j]) | ((u32)bf16rn(acc[3][j]) << 16);
            u32 w2 = (u32)bf16rn(acc[4][j]) | ((u32)bf16rn(acc[5][j]) << 16);
            u32 w3 = (u32)bf16rn(acc[6][j]) | ((u32)bf16rn(acc[7][j]) << 16);
            *(uint4*)(msg + (size_t)v * 64 + 4 * l15) = make_uint4(w0, w1, w2, w3);
        } else {
            int n = v - cap;
            float* dst = out + (size_t)n * COUT + l15;
            #pragma unroll
            for (int cn = 0; cn < 8; ++cn)
                atomicAdd(dst + cn * 16, acc[cn][j]);
        }
    }
}

// ---------------- phase B (wmode=1): uint4 segment-sum + fused stats ----------------
__global__ void convB_stats_k(const u32* __restrict__ msg, const int* __restrict__ offs,
                              float* __restrict__ out, float* __restrict__ stats,
                              int N, int cap, int nblk)
{
    const int tid = threadIdx.x;
    const int wave = tid >> 6, lane = tid & 63;
    const int sub = lane >> 4, l15 = lane & 15;
    const int colA = l15 + 32 * sub;
    float sA = 0.f, qA = 0.f, sB = 0.f, qB = 0.f;

    for (int n = blockIdx.x * 4 + wave; n < N; n += nblk * 4) {
        int s = min(offs[n], cap), e = min(offs[n + 1], cap);
        float a0 = 0.f, a1 = 0.f, a2 = 0.f, a3 = 0.f;
        float b0 = 0.f, b1 = 0.f, b2 = 0.f, b3 = 0.f;
        for (int r = s; r < e; r += 4) {
            int ent = r + sub;
            uint4 v = make_uint4(0u, 0u, 0u, 0u);
            if (ent < e) v = *(const uint4*)(msg + (size_t)ent * 64 + 4 * l15);
            a0 += __uint_as_float(v.x << 16); b0 += __uint_as_float(v.x & 0xFFFF0000u);
            a1 += __uint_as_float(v.y << 16); b1 += __uint_as_float(v.y & 0xFFFF0000u);
            a2 += __uint_as_float(v.z << 16); b2 += __uint_as_float(v.z & 0xFFFF0000u);
            a3 += __uint_as_float(v.w << 16); b3 += __uint_as_float(v.w & 0xFFFF0000u);
        }
        #define RED4(x) { x += __shfl_xor(x, 16, 64); x += __shfl_xor(x, 32, 64); }
        RED4(a0) RED4(a1) RED4(a2) RED4(a3)
        RED4(b0) RED4(b1) RED4(b2) RED4(b3)
        #undef RED4
        float va = (sub == 0) ? a0 : (sub == 1) ? a1 : (sub == 2) ? a2 : a3;
        float vb = (sub == 0) ? b0 : (sub == 1) ? b1 : (sub == 2) ? b2 : b3;
        float* po = out + (size_t)n * COUT;
        po[colA]      = va;
        po[colA + 16] = vb;
        sA += va; qA += va * va;
        sB += vb; qB += vb * vb;
    }

    __shared__ float st[4][64][4];
    st[wave][lane][0] = sA; st[wave][lane][1] = qA;
    st[wave][lane][2] = sB; st[wave][lane][3] = qB;
    __syncthreads();
    int lane2 = tid >> 2, slot = tid & 3;
    float sum = st[0][lane2][slot] + st[1][lane2][slot]
              + st[2][lane2][slot] + st[3][lane2][slot];
    int colb = (lane2 & 15) + 32 * (lane2 >> 4) + ((slot >= 2) ? 16 : 0);
    atomicAdd(&stats[((slot & 1) ? 128 : 0) + colb], sum);
}

// ---------------- phase B (wmode=0): += segment-sum (composes with atomics) ----
__global__ void convB_k(const u32* __restrict__ msg, const int* __restrict__ offs,
                        float* __restrict__ out, int N, int cap)
{
    int wave = threadIdx.x >> 6, lane = threadIdx.x & 63;
    int n = blockIdx.x * 4 + wave;
    if (n >= N) return;
    int s = min(offs[n], cap), e = min(offs[n + 1], cap);
    float a0 = 0.f, a1 = 0.f;
    int r = s;
    for (; r + 2 <= e; r += 2) {
        u32 v0 = msg[(size_t)r * 64 + lane];
        u32 v1 = msg[(size_t)(r + 1) * 64 + lane];
        a0 += __uint_as_float(v0 << 16) + __uint_as_float(v1 << 16);
        a1 += __uint_as_float(v0 & 0xFFFF0000u) + __uint_as_float(v1 & 0xFFFF0000u);
    }
    if (r < e) {
        u32 v0 = msg[(size_t)r * 64 + lane];
        a0 += __uint_as_float(v0 << 16);
        a1 += __uint_as_float(v0 & 0xFFFF0000u);
    }
    int c0 = (lane >> 2) + ((lane & 3) << 5);
    float* po = out + (size_t)n * COUT;
    po[c0]      += a0;
    po[c0 + 16] += a1;
}

// ---------------- fallback atomic conv (frag-linear Wt) ----------------
__launch_bounds__(256, 2)
__global__ void conv_k(const u16* __restrict__ fb, const u16* __restrict__ Wt,
                       const int* __restrict__ in_idx, const int* __restrict__ out_idx,
                       const int* __restrict__ valid, float* __restrict__ out, int N)
{
    __shared__ __align__(16) u16 Asub[BM * LDA];
    __shared__ __align__(16) u16 Bsub[COUT * CIN];   // fragment-linear
    __shared__ int orow[BM];

    const int tile = blockIdx.x;
    const int k = blockIdx.y;
    const int tid = threadIdx.x;
    const int m0 = tile * BM;

    {
        const u16* wk = Wt + ((size_t)k << 14);
        #pragma unroll
        for (int j = 0; j < 8; ++j)
            *(uint4*)(Bsub + j * 2048 + tid * 8) = *(const uint4*)(wk + j * 2048 + tid * 8);
    }
    {
        int r = tid >> 1, half = tid & 1;
        int m = m0 + r;
        int act = 0, ii = 0, oi = -1;
        if (m < N) {
            int base = k * N + m;
            act = valid[base];
            ii  = in_idx[base];
            oi  = out_idx[base];
        }
        if (half == 0) orow[r] = (m < N && act > 0) ? oi : -1;
        if (m < N && act > 0) {
            const u16* src = fb + (size_t)ii * CIN + half * 64;
            u16* dst = Asub + r * LDA + half * 64;
            #pragma unroll
            for (int j = 0; j < 8; ++j)
                *(uint4*)(dst + j * 8) = *(const uint4*)(src + j * 8);
        }
    }
    __syncthreads();

    const int wave = tid >> 6, lane = tid & 63;
    const int l15 = lane & 15, l4 = lane >> 4;

    f32x4 acc[2][8];
    #pragma unroll
    for (int x = 0; x < 2; ++x)
        #pragma unroll
        for (int y = 0; y < 8; ++y)
            acc[x][y] = (f32x4){0.f, 0.f, 0.f, 0.f};

    #pragma unroll
    for (int kk = 0; kk < 4; ++kk) {
        const int coff = kk * 32 + l4 * 8;
        bf16x8 a0 = *(const bf16x8*)(Asub + (wave * 32 + l15) * LDA + coff);
        bf16x8 a1 = *(const bf16x8*)(Asub + (wave * 32 + 16 + l15) * LDA + coff);
        #pragma unroll
        for (int cn = 0; cn < 8; ++cn) {
            bf16x8 b = *(const bf16x8*)(Bsub + (((cn << 2) + kk) << 9) + lane * 8);
            acc[0][cn] = __builtin_amdgcn_mfma_f32_16x16x32_bf16(a0, b, acc[0][cn], 0, 0, 0);
            acc[1][cn] = __builtin_amdgcn_mfma_f32_16x16x32_bf16(a1, b, acc[1][cn], 0, 0, 0);
        }
    }

    #pragma unroll
    for (int rm = 0; rm < 2; ++rm) {
        #pragma unroll
        for (int j = 0; j < 4; ++j) {
            int rl = wave * 32 + rm * 16 + l4 * 4 + j;
            int od = orow[rl];
            if (od >= 0) {
                float* dst = out + (size_t)od * COUT + l15;
                #pragma unroll
                for (int cn = 0; cn < 8; ++cn)
                    atomicAdd(dst + cn * 16, acc[rm][cn][j]);
            }
        }
    }
}

// ---------------- stats / BN+GELU ----------------
__global__ void stats_k(const float* __restrict__ out, float* __restrict__ stats, int N) {
    const int tid = threadIdx.x;
    const int col = tid & 127;
    const int pr = tid >> 7;
    float s = 0.f, sq = 0.f;
    for (int r = blockIdx.x * 2 + pr; r < N; r += gridDim.x * 2) {
        float v = out[(size_t)r * COUT + col];
        s += v; sq += v * v;
    }
    __shared__ float red[512];
    red[tid] = s;
    red[256 + tid] = sq;
    __syncthreads();
    if (tid < 128) {
        atomicAdd(&stats[col],       red[tid] + red[tid + 128]);
        atomicAdd(&stats[128 + col], red[256 + tid] + red[384 + tid]);
    }
}

__global__ void finalize_k(float* __restrict__ stats, const float* __restrict__ gamma,
                           const float* __restrict__ beta, float invN) {
    int c = threadIdx.x;   // 128 threads
    float mean = stats[c] * invN;
    float var = stats[128 + c] * invN - mean * mean;
    float sc = rsqrtf(var + 1e-5f) * gamma[c];
    stats[256 + c] = sc;
    stats[384 + c] = beta[c] - mean * sc;
}

__global__ void bngelu_k(float* __restrict__ out, const float* __restrict__ stats, int total4) {
    int i = blockIdx.x * blockDim.x + threadIdx.x;
    if (i >= total4) return;
    float4 v = ((const float4*)out)[i];
    int cb = (i << 2) & 127;
    float r[4] = {v.x, v.y, v.z, v.w};
    #pragma unroll
    for (int e = 0; e < 4; ++e) {
        int c = cb + e;
        float y = r[e] * stats[256 + c] + stats[384 + c];
        r[e] = 0.5f * y * (1.0f + erff(y * 0.70710678118f));
    }
    ((float4*)out)[i] = make_float4(r[0], r[1], r[2], r[3]);
}

extern "C" void kernel_launch(void* const* d_in, const int* in_sizes, int n_in,
                              void* d_out, int out_size, void* d_ws, size_t ws_size,
                              hipStream_t stream) {
    const float* feats  = (const float*)d_in[0];
    const float* W      = (const float*)d_in[1];
    const float* gamma  = (const float*)d_in[2];
    const float* beta   = (const float*)d_in[3];
    const int*   in_idx = (const int*)d_in[4];
    const int*   outidx = (const int*)d_in[5];
    const int*   valid  = (const int*)d_in[6];
    const int N = in_sizes[0] / CIN;          // 40000
    const int K = in_sizes[1] / (CIN * COUT); // 27
    const int E = K * N;
    float* out = (float*)d_out;

    const int nb  = (N + 255) / 256;          // scan blocks (157) — must be <= 1024
    const int nbE = (E + 255) / 256;          // entry blocks (4219)

    const size_t fbB   = ((size_t)N * CIN * 2 + 255) & ~255ull;
    const size_t WtB   = ((size_t)K * CIN * COUT * 2 + 255) & ~255ull;
    const size_t cinB  = ((size_t)E * 4 + 255) & ~255ull;
    const size_t cposB = cinB;
    const size_t posB  = cinB;                                   // pos[E]
    const size_t cntB  = ((size_t)N * 4 + 255) & ~255ull;       // cnt[N]
    const size_t kcB   = 256;                                    // kcount[K]
    const size_t stB   = 2048;                                   // stats[512]
    const size_t offsB = ((size_t)(N + 1) * 4 + 255) & ~255ull;
    const size_t bsB   = ((size_t)nb * 4 + 255) & ~255ull;       // block sums
    const size_t nbEB  = ((size_t)nbE * 4 + 255) & ~255ull;      // bc0/bc1/base0/base1
    const size_t fixedB = fbB + WtB + cinB + cposB + posB + cntB + kcB + stB + offsB
                        + bsB + 4 * nbEB + 1024;

    int total8 = N * CIN / 8;
    int totalw = K * CIN * COUT;

    if (ws_size >= fixedB + (size_t)1024 * 256 && nb <= 1024 && nb + 1 <= 256) {
        long long capL = ((long long)ws_size - (long long)fixedB) / 256;
        if (capL > (long long)E) capL = E;
        const int cap = (int)capL;
        const int wmode = (cap >= E) ? 1 : 0;   // no overflow atomics possible

        char* w = (char*)d_ws;
        u32* msg      = (u32*)w;  w += (size_t)cap * 256;
        u16* fb       = (u16*)w;  w += fbB;
        u16* Wt       = (u16*)w;  w += WtB;
        int* cin_arr  = (int*)w;  w += cinB;
        int* cpos_arr = (int*)w;  w += cposB;
        int* pos      = (int*)w;  w += posB;
        int* cnt      = (int*)w;  w += cntB;   // cnt | kcount | stats contiguous
        int* kcount   = (int*)w;  w += kcB;
        float* stats  = (float*)w; w += stB;
        int* offs     = (int*)w;  w += offsB;
        int* bsum     = (int*)w;  w += bsB;
        int* bc0      = (int*)w;  w += nbEB;
        int* bc1      = (int*)w;  w += nbEB;
        int* base0    = (int*)w;  w += nbEB;
        int* base1    = (int*)w;

        if (!wmode)
            hipMemsetAsync(out, 0, (size_t)N * COUT * sizeof(float), stream);
        hipMemsetAsync(cnt, 0, cntB + kcB + stB, stream);

        const int b0 = (total8 + 255) / 256;
        const int b1 = (totalw + 255) / 256;
        prep_k<<<b0 + b1 + nbE, 256, 0, stream>>>(feats, W, outidx, valid, fb, Wt,
                                                  cnt, pos, bc0, bc1,
                                                  total8, totalw, N, E, b0, b1);
        scan_sum_k<<<nb, 256, 0, stream>>>(cnt, bsum, N);
        scan_top_k<<<1, 1024, 0, stream>>>(bsum, nb);
        scan_apply_kscan_k<<<nb + K, 256, 0, stream>>>(cnt, bsum, offs, bc0, bc1,
                                                       base0, base1, kcount, N, nb);
        rank_k<<<nbE, 256, 0, stream>>>(outidx, in_idx, valid, pos, offs,
                                        base0, base1, cin_arr, cpos_arr, N, E, cap);

        dim3 gA((N + BM - 1) / BM, K);
        convA_k<<<gA, 512, 0, stream>>>(fb, Wt, cin_arr, cpos_arr, kcount, msg, out, N, cap);

        if (wmode) {
            const int nblk = 2048;
            convB_stats_k<<<nblk, 256, 0, stream>>>(msg, offs, out, stats, N, cap, nblk);
        } else {
            convB_k<<<(N + 3) / 4, 256, 0, stream>>>(msg, offs, out, N, cap);
            stats_k<<<256, 256, 0, stream>>>(out, stats, N);
        }

        finalize_k<<<1, 128, 0, stream>>>(stats, gamma, beta, 1.0f / (float)N);
        bngelu_k<<<(N * COUT / 4 + 255) / 256, 256, 0, stream>>>(out, stats, N * COUT / 4);
    } else {
        // minimal-ws fallback: atomic path (~11.4 MB)
        u16* fb = (u16*)d_ws;
        u16* Wt = fb + (size_t)N * CIN;
        float* stats = (float*)(Wt + (size_t)K * CIN * COUT);

        hipMemsetAsync(out, 0, (size_t)N * COUT * sizeof(float), stream);
        hipMemsetAsync(stats, 0, 256 * sizeof(float), stream);

        precast_feats_k<<<(total8 + 255) / 256, 256, 0, stream>>>(feats, fb, total8);
        precast_w_k<<<(totalw + 255) / 256, 256, 0, stream>>>(W, Wt, totalw);

        dim3 g((N + BM - 1) / BM, K);
        conv_k<<<g, 256, 0, stream>>>(fb, Wt, in_idx, outidx, valid, out, N);

        stats_k<<<256, 256, 0, stream>>>(out, stats, N);
        finalize_k<<<1, 128, 0, stream>>>(stats, gamma, beta, 1.0f / (float)N);
        bngelu_k<<<(N * COUT / 4 + 255) / 256, 256, 0, stream>>>(out, stats, N * COUT / 4);
    }
}

// Round 17
// 167.582 us; speedup vs baseline: 2.5619x; 1.0484x over previous
//
#include <hip/hip_runtime.h>

typedef unsigned short u16;
typedef unsigned int u32;
typedef unsigned long long u64;
using f32x4 = __attribute__((ext_vector_type(4))) float;
using bf16x8 = __attribute__((ext_vector_type(8))) short;

#define CIN 128
#define COUT 128
#define BM 128
#define LDA 136  // padded LDS row stride for Asub in fallback kernel only

__device__ inline u16 bf16rn(float f) {
    union { float f; u32 u; } v; v.f = f;
    u32 u = v.u;
    u += 0x7FFFu + ((u >> 16) & 1u);   // round-to-nearest-even
    return (u16)(u >> 16);
}

// ---------------- fallback-path precasts (also used as prep_k bodies) ----------------
__global__ void precast_feats_k(const float* __restrict__ in, u16* __restrict__ out, int total8) {
    int i = blockIdx.x * blockDim.x + threadIdx.x;
    if (i >= total8) return;
    const float4* p = (const float4*)in + 2 * (size_t)i;
    float4 a = p[0], b = p[1];
    u32 o0 = (u32)bf16rn(a.x) | ((u32)bf16rn(a.y) << 16);
    u32 o1 = (u32)bf16rn(a.z) | ((u32)bf16rn(a.w) << 16);
    u32 o2 = (u32)bf16rn(b.x) | ((u32)bf16rn(b.y) << 16);
    u32 o3 = (u32)bf16rn(b.z) | ((u32)bf16rn(b.w) << 16);
    ((uint4*)out)[i] = make_uint4(o0, o1, o2, o3);
}

// Wt fragment-linear layout: Wt[k][frag][lane][e], frag = cn*4+kk (32 frags).
// Element = W[k][c][d], d = cn*16 + (lane&15), c = kk*32 + (lane>>4)*8 + e.
// LDS staging is a pure linear memcpy; inner ds_read_b128 at lane*16B is
// conflict-free (verified r11: SQ_LDS_BANK_CONFLICT 5.4M -> 0).
__global__ void precast_w_k(const float* __restrict__ W, u16* __restrict__ Wt, int total) {
    int i = blockIdx.x * blockDim.x + threadIdx.x;
    if (i >= total) return;
    int k = i >> 14;
    int rem = i & 16383;
    int f = rem >> 9;          // frag 0..31
    int l = (rem >> 3) & 63;   // lane
    int e = rem & 7;
    int cn = f >> 2, kk = f & 3;
    int d = cn * 16 + (l & 15);
    int c = kk * 32 + ((l >> 4) << 3) + e;
    Wt[i] = bf16rn(W[(k << 14) + (c << 7) + d]);
}

// ---------------- fused prep: precast feats || precast W || hist ----------------
__global__ void prep_k(const float* __restrict__ feats, const float* __restrict__ W,
                       const int* __restrict__ oi, const int* __restrict__ valid,
                       u16* __restrict__ fb, u16* __restrict__ Wt,
                       int* __restrict__ cnt, int* __restrict__ pos,
                       int* __restrict__ bc0, int* __restrict__ bc1,
                       int total8, int totalw, int N, int E, int b0, int b1) {
    const int blk = blockIdx.x;
    const int tid = threadIdx.x;
    if (blk < b0) {
        int i = blk * 256 + tid;
        if (i >= total8) return;
        const float4* p = (const float4*)feats + 2 * (size_t)i;
        float4 a = p[0], q = p[1];
        u32 o0 = (u32)bf16rn(a.x) | ((u32)bf16rn(a.y) << 16);
        u32 o1 = (u32)bf16rn(a.z) | ((u32)bf16rn(a.w) << 16);
        u32 o2 = (u32)bf16rn(q.x) | ((u32)bf16rn(q.y) << 16);
        u32 o3 = (u32)bf16rn(q.z) | ((u32)bf16rn(q.w) << 16);
        ((uint4*)fb)[i] = make_uint4(o0, o1, o2, o3);
    } else if (blk < b0 + b1) {
        int i = (blk - b0) * 256 + tid;
        if (i >= totalw) return;
        int k = i >> 14;
        int rem = i & 16383;
        int f = rem >> 9;
        int l = (rem >> 3) & 63;
        int e = rem & 7;
        int cn = f >> 2, kk = f & 3;
        int d = cn * 16 + (l & 15);
        int c = kk * 32 + ((l >> 4) << 3) + e;
        Wt[i] = bf16rn(W[(k << 14) + (c << 7) + d]);
    } else {
        const int b = blk - b0 - b1;            // local hist block index
        const int e = b * 256 + tid;
        const int k0 = (b * 256) / N;
        bool v = false; bool g = false;
        if (e < E) {
            v = valid[e] > 0;
            g = (e >= (k0 + 1) * N);
            if (v) pos[e] = atomicAdd(&cnt[oi[e]], 1);
        }
        const int lane = tid & 63, wid = tid >> 6;
        u64 m0 = __ballot(v && !g);
        u64 m1 = __ballot(v && g);
        __shared__ int wt[4][2];
        if (lane == 0) { wt[wid][0] = __popcll(m0); wt[wid][1] = __popcll(m1); }
        __syncthreads();
        if (tid == 0) bc0[b] = wt[0][0] + wt[1][0] + wt[2][0] + wt[3][0];
        if (tid == 1) bc1[b] = wt[0][1] + wt[1][1] + wt[2][1] + wt[3][1];
    }
}

// ---------------- fallback-path hist (unfused) ----------------
__global__ void hist_k(const int* __restrict__ oi, const int* __restrict__ valid,
                       int* __restrict__ cnt, int* __restrict__ pos,
                       int* __restrict__ bc0, int* __restrict__ bc1, int N, int E) {
    const int tid = threadIdx.x;
    const int b = blockIdx.x;
    const int e = b * 256 + tid;
    const int k0 = (b * 256) / N;
    bool v = false; bool g = false;
    if (e < E) {
        v = valid[e] > 0;
        g = (e >= (k0 + 1) * N);
        if (v) pos[e] = atomicAdd(&cnt[oi[e]], 1);
    }
    const int lane = tid & 63, wid = tid >> 6;
    u64 m0 = __ballot(v && !g);
    u64 m1 = __ballot(v && g);
    __shared__ int wt[4][2];
    if (lane == 0) { wt[wid][0] = __popcll(m0); wt[wid][1] = __popcll(m1); }
    __syncthreads();
    if (tid == 0) bc0[b] = wt[0][0] + wt[1][0] + wt[2][0] + wt[3][0];
    if (tid == 1) bc1[b] = wt[0][1] + wt[1][1] + wt[2][1] + wt[3][1];
}

// ---- hierarchical exclusive scan of cnt[N] -> offs[N+1] ----
__global__ void scan_sum_k(const int* __restrict__ cnt, int* __restrict__ bsum, int N) {
    __shared__ int red[256];
    int t = threadIdx.x;
    int i = blockIdx.x * 256 + t;
    red[t] = (i < N) ? cnt[i] : 0;
    __syncthreads();
    #pragma unroll
    for (int d = 128; d > 0; d >>= 1) {
        if (t < d) red[t] += red[t + d];
        __syncthreads();
    }
    if (t == 0) bsum[blockIdx.x] = red[0];
}

__global__ void scan_top_k(int* __restrict__ bsum, int nb) {
    __shared__ int part[1024];
    int t = threadIdx.x;
    int v = (t < nb) ? bsum[t] : 0;
    part[t] = v;
    __syncthreads();
    for (int d = 1; d < 1024; d <<= 1) {
        int x = (t >= d) ? part[t - d] : 0;
        __syncthreads();
        part[t] += x;
        __syncthreads();
    }
    if (t < nb) bsum[t] = part[t] - v;   // exclusive
}

// ---------------- fused scan_apply || kscan (block-range split) ----------------
__global__ void scan_apply_kscan_k(const int* __restrict__ cnt, const int* __restrict__ bsum,
                                   int* __restrict__ offs,
                                   const int* __restrict__ bc0, const int* __restrict__ bc1,
                                   int* __restrict__ base0, int* __restrict__ base1,
                                   int* __restrict__ kcount, int N, int nb) {
    const int t = threadIdx.x;
    __shared__ int part[256];
    if ((int)blockIdx.x < nb) {
        int i = blockIdx.x * 256 + t;
        int v = (i < N) ? cnt[i] : 0;
        part[t] = v;
        __syncthreads();
        #pragma unroll
        for (int d = 1; d < 256; d <<= 1) {
            int x = (t >= d) ? part[t - d] : 0;
            __syncthreads();
            part[t] += x;
            __syncthreads();
        }
        int base = bsum[blockIdx.x];
        if (i < N) {
            int excl = base + part[t] - v;
            offs[i] = excl;
            if (i == N - 1) offs[N] = excl + v;
        }
    } else {
        const int k = blockIdx.x - nb;
        const int blo = (k * N) / 256;
        const int bhi = ((k + 1) * N - 1) / 256;
        const int len = bhi - blo + 1;        // <= 256 (guarded host-side)
        const int b = blo + t;
        int k0b = 0, contrib = 0;
        const bool inr = (t < len);
        if (inr) {
            k0b = (b * 256) / N;
            contrib = (k0b == k) ? bc0[b] : bc1[b];
        }
        part[t] = contrib;
        __syncthreads();
        #pragma unroll
        for (int d = 1; d < 256; d <<= 1) {
            int x = (t >= d) ? part[t - d] : 0;
            __syncthreads();
            part[t] += x;
            __syncthreads();
        }
        if (inr) {
            int excl = part[t] - contrib;
            if (k0b == k) base0[b] = excl; else base1[b] = excl;
            if (t == len - 1) kcount[k] = part[t];
        }
    }
}

// ---------------- rank: fully atomic-free ----------------
__global__ void rank_k(const int* __restrict__ oi, const int* __restrict__ ini,
                       const int* __restrict__ valid, const int* __restrict__ pos,
                       const int* __restrict__ offs,
                       const int* __restrict__ base0, const int* __restrict__ base1,
                       int* __restrict__ cin_arr, int* __restrict__ cpos_arr,
                       int N, int E, int cap) {
    const int tid = threadIdx.x;
    const int b = blockIdx.x;
    const int e = b * 256 + tid;
    const int k0 = (b * 256) / N;
    bool v = false; int k = 0, n = 0, ii = 0, p = 0;
    if (e < E) {
        v = valid[e] > 0;
        k = (e >= (k0 + 1) * N) ? k0 + 1 : k0;
        if (v) { n = oi[e]; ii = ini[e]; p = pos[e]; }
    }
    const int g = k - k0;   // 0 or 1
    const int lane = tid & 63, wid = tid >> 6;
    u64 m0 = __ballot(v && g == 0);
    u64 m1 = __ballot(v && g == 1);
    u64 lt = (1ull << lane) - 1ull;
    int r0 = __popcll(m0 & lt);
    int r1 = __popcll(m1 & lt);
    __shared__ int wt[4][2];
    if (lane == 0) { wt[wid][0] = __popcll(m0); wt[wid][1] = __popcll(m1); }
    __syncthreads();
    if (v) {
        int wbase = 0;
        #pragma unroll
        for (int w2 = 0; w2 < 4; ++w2) if (w2 < wid) wbase += wt[w2][g];
        int kb = g ? base1[b] : base0[b];
        int slot = kb + wbase + (g ? r1 : r0);
        int pg = offs[n] + p;
        cin_arr[k * N + slot] = ii;
        cpos_arr[k * N + slot] = (pg < cap) ? pg : (cap + n);
    }
}

// ---------------- phase A: gather + GEMM + sorted store (r13 verified best) ----------------
// 512 threads, 8 waves, 16 rows/wave, one 128-row tile per block (NO
// persistent loop: r14/r15 loop-carried variants spilled a0/acc to scratch —
// FETCH 61->600+ MB — and regressed 2.5x; this exact body measured 47 us,
// FETCH 61 MB, VGPR 32, 0 bank conflicts). B staged via linear memcpy of
// fragment-order Wt; A gathered into registers in MFMA layout before staging;
// cpos read post-MFMA.
// msg row layout: word w = 4*l15 + q holds packed bf16 cols (l15+32q, l15+32q+16)
__launch_bounds__(512, 6)
__global__ void convA_k(const u16* __restrict__ fb, const u16* __restrict__ Wt,
                        const int* __restrict__ cin_arr, const int* __restrict__ cpos_arr,
                        const int* __restrict__ kcount, u32* __restrict__ msg,
                        float* __restrict__ out, int N, int cap)
{
    const int k = blockIdx.y;
    const int kc = kcount[k];
    const int m0 = blockIdx.x * BM;
    if (m0 >= kc) return;

    __shared__ __align__(16) u16 Bsub[COUT * CIN];   // 32 KB, fragment-linear

    const int tid = threadIdx.x;
    const int wave = tid >> 6, lane = tid & 63;
    const int l15 = lane & 15, l4 = lane >> 4;
    const int base = k * N;

    // A fragments: global -> regs, MFMA layout. One 16-row set per wave.
    int r0 = m0 + wave * 16 + l15;
    int i0 = cin_arr[base + min(r0, kc - 1)];
    if (r0 >= kc) i0 = 0;   // read valid memory; result rows are discarded
    const u16* pa0 = fb + (size_t)i0 * CIN + l4 * 8;
    bf16x8 a0[4];
    #pragma unroll
    for (int kk = 0; kk < 4; ++kk)
        a0[kk] = *(const bf16x8*)(pa0 + kk * 32);

    // stage W[k] (fragment-order, 32 KB) into LDS: pure linear memcpy
    {
        const u16* wk = Wt + ((size_t)k << 14);
        #pragma unroll
        for (int j = 0; j < 4; ++j)
            *(uint4*)(Bsub + j * 4096 + tid * 8) = *(const uint4*)(wk + j * 4096 + tid * 8);
    }
    __syncthreads();

    f32x4 acc[8];
    #pragma unroll
    for (int y = 0; y < 8; ++y)
        acc[y] = (f32x4){0.f, 0.f, 0.f, 0.f};

    #pragma unroll
    for (int kk = 0; kk < 4; ++kk) {
        #pragma unroll
        for (int cn = 0; cn < 8; ++cn) {
            bf16x8 b = *(const bf16x8*)(Bsub + (((cn << 2) + kk) << 9) + lane * 8);
            acc[cn] = __builtin_amdgcn_mfma_f32_16x16x32_bf16(a0[kk], b, acc[cn], 0, 0, 0);
        }
    }

    #pragma unroll
    for (int j = 0; j < 4; ++j) {
        int rl = m0 + wave * 16 + l4 * 4 + j;
        if (rl >= kc) continue;
        int v = cpos_arr[base + rl];   // 16 lanes share each addr -> broadcast
        if (v < cap) {
            u32 w0 = (u32)bf16rn(acc[0][j]) | ((u32)bf16rn(acc[1][j]) << 16);
            u32 w1 = (u32)bf16rn(acc[2][j]) | ((u32)bf16rn(acc[3][j]) << 16);
            u32 w2 = (u32)bf16rn(acc[4][j]) | ((u32)bf16rn(acc[5][j]) << 16);
            u32 w3 = (u32)bf16rn(acc[6][j]) | ((u32)bf16rn(acc[7][j]) << 16);
            *(uint4*)(msg + (size_t)v * 64 + 4 * l15) = make_uint4(w0, w1, w2, w3);
        } else {
            int n = v - cap;
            float* dst = out + (size_t)n * COUT + l15;
            #pragma unroll
            for (int cn = 0; cn < 8; ++cn)
                atomicAdd(dst + cn * 16, acc[cn][j]);
        }
    }
}

// ---------------- phase B (wmode=1): uint4 segment-sum + fused stats ----------------
__global__ void convB_stats_k(const u32* __restrict__ msg, const int* __restrict__ offs,
                              float* __restrict__ out, float* __restrict__ stats,
                              int N, int cap, int nblk)
{
    const int tid = threadIdx.x;
    const int wave = tid >> 6, lane = tid & 63;
    const int sub = lane >> 4, l15 = lane & 15;
    const int colA = l15 + 32 * sub;
    float sA = 0.f, qA = 0.f, sB = 0.f, qB = 0.f;

    for (int n = blockIdx.x * 4 + wave; n < N; n += nblk * 4) {
        int s = min(offs[n], cap), e = min(offs[n + 1], cap);
        float a0 = 0.f, a1 = 0.f, a2 = 0.f, a3 = 0.f;
        float b0 = 0.f, b1 = 0.f, b2 = 0.f, b3 = 0.f;
        for (int r = s; r < e; r += 4) {
            int ent = r + sub;
            uint4 v = make_uint4(0u, 0u, 0u, 0u);
            if (ent < e) v = *(const uint4*)(msg + (size_t)ent * 64 + 4 * l15);
            a0 += __uint_as_float(v.x << 16); b0 += __uint_as_float(v.x & 0xFFFF0000u);
            a1 += __uint_as_float(v.y << 16); b1 += __uint_as_float(v.y & 0xFFFF0000u);
            a2 += __uint_as_float(v.z << 16); b2 += __uint_as_float(v.z & 0xFFFF0000u);
            a3 += __uint_as_float(v.w << 16); b3 += __uint_as_float(v.w & 0xFFFF0000u);
        }
        #define RED4(x) { x += __shfl_xor(x, 16, 64); x += __shfl_xor(x, 32, 64); }
        RED4(a0) RED4(a1) RED4(a2) RED4(a3)
        RED4(b0) RED4(b1) RED4(b2) RED4(b3)
        #undef RED4
        float va = (sub == 0) ? a0 : (sub == 1) ? a1 : (sub == 2) ? a2 : a3;
        float vb = (sub == 0) ? b0 : (sub == 1) ? b1 : (sub == 2) ? b2 : b3;
        float* po = out + (size_t)n * COUT;
        po[colA]      = va;
        po[colA + 16] = vb;
        sA += va; qA += va * va;
        sB += vb; qB += vb * vb;
    }

    __shared__ float st[4][64][4];
    st[wave][lane][0] = sA; st[wave][lane][1] = qA;
    st[wave][lane][2] = sB; st[wave][lane][3] = qB;
    __syncthreads();
    int lane2 = tid >> 2, slot = tid & 3;
    float sum = st[0][lane2][slot] + st[1][lane2][slot]
              + st[2][lane2][slot] + st[3][lane2][slot];
    int colb = (lane2 & 15) + 32 * (lane2 >> 4) + ((slot >= 2) ? 16 : 0);
    atomicAdd(&stats[((slot & 1) ? 128 : 0) + colb], sum);
}

// ---------------- phase B (wmode=0): += segment-sum (composes with atomics) ----
__global__ void convB_k(const u32* __restrict__ msg, const int* __restrict__ offs,
                        float* __restrict__ out, int N, int cap)
{
    int wave = threadIdx.x >> 6, lane = threadIdx.x & 63;
    int n = blockIdx.x * 4 + wave;
    if (n >= N) return;
    int s = min(offs[n], cap), e = min(offs[n + 1], cap);
    float a0 = 0.f, a1 = 0.f;
    int r = s;
    for (; r + 2 <= e; r += 2) {
        u32 v0 = msg[(size_t)r * 64 + lane];
        u32 v1 = msg[(size_t)(r + 1) * 64 + lane];
        a0 += __uint_as_float(v0 << 16) + __uint_as_float(v1 << 16);
        a1 += __uint_as_float(v0 & 0xFFFF0000u) + __uint_as_float(v1 & 0xFFFF0000u);
    }
    if (r < e) {
        u32 v0 = msg[(size_t)r * 64 + lane];
        a0 += __uint_as_float(v0 << 16);
        a1 += __uint_as_float(v0 & 0xFFFF0000u);
    }
    int c0 = (lane >> 2) + ((lane & 3) << 5);
    float* po = out + (size_t)n * COUT;
    po[c0]      += a0;
    po[c0 + 16] += a1;
}

// ---------------- fallback atomic conv (frag-linear Wt) ----------------
__launch_bounds__(256, 2)
__global__ void conv_k(const u16* __restrict__ fb, const u16* __restrict__ Wt,
                       const int* __restrict__ in_idx, const int* __restrict__ out_idx,
                       const int* __restrict__ valid, float* __restrict__ out, int N)
{
    __shared__ __align__(16) u16 Asub[BM * LDA];
    __shared__ __align__(16) u16 Bsub[COUT * CIN];   // fragment-linear
    __shared__ int orow[BM];

    const int tile = blockIdx.x;
    const int k = blockIdx.y;
    const int tid = threadIdx.x;
    const int m0 = tile * BM;

    {
        const u16* wk = Wt + ((size_t)k << 14);
        #pragma unroll
        for (int j = 0; j < 8; ++j)
            *(uint4*)(Bsub + j * 2048 + tid * 8) = *(const uint4*)(wk + j * 2048 + tid * 8);
    }
    {
        int r = tid >> 1, half = tid & 1;
        int m = m0 + r;
        int act = 0, ii = 0, oi = -1;
        if (m < N) {
            int base = k * N + m;
            act = valid[base];
            ii  = in_idx[base];
            oi  = out_idx[base];
        }
        if (half == 0) orow[r] = (m < N && act > 0) ? oi : -1;
        if (m < N && act > 0) {
            const u16* src = fb + (size_t)ii * CIN + half * 64;
            u16* dst = Asub + r * LDA + half * 64;
            #pragma unroll
            for (int j = 0; j < 8; ++j)
                *(uint4*)(dst + j * 8) = *(const uint4*)(src + j * 8);
        }
    }
    __syncthreads();

    const int wave = tid >> 6, lane = tid & 63;
    const int l15 = lane & 15, l4 = lane >> 4;

    f32x4 acc[2][8];
    #pragma unroll
    for (int x = 0; x < 2; ++x)
        #pragma unroll
        for (int y = 0; y < 8; ++y)
            acc[x][y] = (f32x4){0.f, 0.f, 0.f, 0.f};

    #pragma unroll
    for (int kk = 0; kk < 4; ++kk) {
        const int coff = kk * 32 + l4 * 8;
        bf16x8 a0 = *(const bf16x8*)(Asub + (wave * 32 + l15) * LDA + coff);
        bf16x8 a1 = *(const bf16x8*)(Asub + (wave * 32 + 16 + l15) * LDA + coff);
        #pragma unroll
        for (int cn = 0; cn < 8; ++cn) {
            bf16x8 b = *(const bf16x8*)(Bsub + (((cn << 2) + kk) << 9) + lane * 8);
            acc[0][cn] = __builtin_amdgcn_mfma_f32_16x16x32_bf16(a0, b, acc[0][cn], 0, 0, 0);
            acc[1][cn] = __builtin_amdgcn_mfma_f32_16x16x32_bf16(a1, b, acc[1][cn], 0, 0, 0);
        }
    }

    #pragma unroll
    for (int rm = 0; rm < 2; ++rm) {
        #pragma unroll
        for (int j = 0; j < 4; ++j) {
            int rl = wave * 32 + rm * 16 + l4 * 4 + j;
            int od = orow[rl];
            if (od >= 0) {
                float* dst = out + (size_t)od * COUT + l15;
                #pragma unroll
                for (int cn = 0; cn < 8; ++cn)
                    atomicAdd(dst + cn * 16, acc[rm][cn][j]);
            }
        }
    }
}

// ---------------- stats / BN+GELU ----------------
__global__ void stats_k(const float* __restrict__ out, float* __restrict__ stats, int N) {
    const int tid = threadIdx.x;
    const int col = tid & 127;
    const int pr = tid >> 7;
    float s = 0.f, sq = 0.f;
    for (int r = blockIdx.x * 2 + pr; r < N; r += gridDim.x * 2) {
        float v = out[(size_t)r * COUT + col];
        s += v; sq += v * v;
    }
    __shared__ float red[512];
    red[tid] = s;
    red[256 + tid] = sq;
    __syncthreads();
    if (tid < 128) {
        atomicAdd(&stats[col],       red[tid] + red[tid + 128]);
        atomicAdd(&stats[128 + col], red[256 + tid] + red[384 + tid]);
    }
}

// BN transform: sc/ofs computed once per BLOCK into LDS from raw sums —
// fp32-arithmetic-identical to the old finalize_k (so bitwise-same output),
// amortized over 1024 elements/block. Removes the serializing 1-block
// finalize dispatch (r4's per-ELEMENT variant regressed; this is per-block).
__global__ void bngelu_k(float* __restrict__ out, const float* __restrict__ stats,
                         const float* __restrict__ gamma, const float* __restrict__ beta,
                         float invN, int total4) {
    __shared__ float sc_s[128], of_s[128];
    int tid = threadIdx.x;
    if (tid < 128) {
        float mean = stats[tid] * invN;
        float var = stats[128 + tid] * invN - mean * mean;
        float sc = rsqrtf(var + 1e-5f) * gamma[tid];
        sc_s[tid] = sc;
        of_s[tid] = beta[tid] - mean * sc;
    }
    __syncthreads();
    int i = blockIdx.x * blockDim.x + tid;
    if (i >= total4) return;
    float4 v = ((const float4*)out)[i];
    int cb = (i << 2) & 127;
    float r[4] = {v.x, v.y, v.z, v.w};
    #pragma unroll
    for (int e = 0; e < 4; ++e) {
        int c = cb + e;
        float y = r[e] * sc_s[c] + of_s[c];
        r[e] = 0.5f * y * (1.0f + erff(y * 0.70710678118f));
    }
    ((float4*)out)[i] = make_float4(r[0], r[1], r[2], r[3]);
}

extern "C" void kernel_launch(void* const* d_in, const int* in_sizes, int n_in,
                              void* d_out, int out_size, void* d_ws, size_t ws_size,
                              hipStream_t stream) {
    const float* feats  = (const float*)d_in[0];
    const float* W      = (const float*)d_in[1];
    const float* gamma  = (const float*)d_in[2];
    const float* beta   = (const float*)d_in[3];
    const int*   in_idx = (const int*)d_in[4];
    const int*   outidx = (const int*)d_in[5];
    const int*   valid  = (const int*)d_in[6];
    const int N = in_sizes[0] / CIN;          // 40000
    const int K = in_sizes[1] / (CIN * COUT); // 27
    const int E = K * N;
    float* out = (float*)d_out;

    const int nb  = (N + 255) / 256;          // scan blocks (157) — must be <= 1024
    const int nbE = (E + 255) / 256;          // entry blocks (4219)

    const size_t fbB   = ((size_t)N * CIN * 2 + 255) & ~255ull;
    const size_t WtB   = ((size_t)K * CIN * COUT * 2 + 255) & ~255ull;
    const size_t cinB  = ((size_t)E * 4 + 255) & ~255ull;
    const size_t cposB = cinB;
    const size_t posB  = cinB;                                   // pos[E]
    const size_t cntB  = ((size_t)N * 4 + 255) & ~255ull;       // cnt[N]
    const size_t kcB   = 256;                                    // kcount[K]
    const size_t stB   = 2048;                                   // stats[512]
    const size_t offsB = ((size_t)(N + 1) * 4 + 255) & ~255ull;
    const size_t bsB   = ((size_t)nb * 4 + 255) & ~255ull;       // block sums
    const size_t nbEB  = ((size_t)nbE * 4 + 255) & ~255ull;      // bc0/bc1/base0/base1
    const size_t fixedB = fbB + WtB + cinB + cposB + posB + cntB + kcB + stB + offsB
                        + bsB + 4 * nbEB + 1024;

    int total8 = N * CIN / 8;
    int totalw = K * CIN * COUT;

    if (ws_size >= fixedB + (size_t)1024 * 256 && nb <= 1024 && nb + 1 <= 256) {
        long long capL = ((long long)ws_size - (long long)fixedB) / 256;
        if (capL > (long long)E) capL = E;
        const int cap = (int)capL;
        const int wmode = (cap >= E) ? 1 : 0;   // no overflow atomics possible

        char* w = (char*)d_ws;
        u32* msg      = (u32*)w;  w += (size_t)cap * 256;
        u16* fb       = (u16*)w;  w += fbB;
        u16* Wt       = (u16*)w;  w += WtB;
        int* cin_arr  = (int*)w;  w += cinB;
        int* cpos_arr = (int*)w;  w += cposB;
        int* pos      = (int*)w;  w += posB;
        int* cnt      = (int*)w;  w += cntB;   // cnt | kcount | stats contiguous
        int* kcount   = (int*)w;  w += kcB;
        float* stats  = (float*)w; w += stB;
        int* offs     = (int*)w;  w += offsB;
        int* bsum     = (int*)w;  w += bsB;
        int* bc0      = (int*)w;  w += nbEB;
        int* bc1      = (int*)w;  w += nbEB;
        int* base0    = (int*)w;  w += nbEB;
        int* base1    = (int*)w;

        if (!wmode)
            hipMemsetAsync(out, 0, (size_t)N * COUT * sizeof(float), stream);
        hipMemsetAsync(cnt, 0, cntB + kcB + stB, stream);

        const int b0 = (total8 + 255) / 256;
        const int b1 = (totalw + 255) / 256;
        prep_k<<<b0 + b1 + nbE, 256, 0, stream>>>(feats, W, outidx, valid, fb, Wt,
                                                  cnt, pos, bc0, bc1,
                                                  total8, totalw, N, E, b0, b1);
        scan_sum_k<<<nb, 256, 0, stream>>>(cnt, bsum, N);
        scan_top_k<<<1, 1024, 0, stream>>>(bsum, nb);
        scan_apply_kscan_k<<<nb + K, 256, 0, stream>>>(cnt, bsum, offs, bc0, bc1,
                                                       base0, base1, kcount, N, nb);
        rank_k<<<nbE, 256, 0, stream>>>(outidx, in_idx, valid, pos, offs,
                                        base0, base1, cin_arr, cpos_arr, N, E, cap);

        dim3 gA((N + BM - 1) / BM, K);
        convA_k<<<gA, 512, 0, stream>>>(fb, Wt, cin_arr, cpos_arr, kcount, msg, out, N, cap);

        if (wmode) {
            const int nblk = 2048;
            convB_stats_k<<<nblk, 256, 0, stream>>>(msg, offs, out, stats, N, cap, nblk);
        } else {
            convB_k<<<(N + 3) / 4, 256, 0, stream>>>(msg, offs, out, N, cap);
            stats_k<<<256, 256, 0, stream>>>(out, stats, N);
        }

        bngelu_k<<<(N * COUT / 4 + 255) / 256, 256, 0, stream>>>(out, stats, gamma, beta,
                                                                 1.0f / (float)N, N * COUT / 4);
    } else {
        // minimal-ws fallback: atomic path (~11.4 MB)
        u16* fb = (u16*)d_ws;
        u16* Wt = fb + (size_t)N * CIN;
        float* stats = (float*)(Wt + (size_t)K * CIN * COUT);

        hipMemsetAsync(out, 0, (size_t)N * COUT * sizeof(float), stream);
        hipMemsetAsync(stats, 0, 256 * sizeof(float), stream);

        precast_feats_k<<<(total8 + 255) / 256, 256, 0, stream>>>(feats, fb, total8);
        precast_w_k<<<(totalw + 255) / 256, 256, 0, stream>>>(W, Wt, totalw);

        dim3 g((N + BM - 1) / BM, K);
        conv_k<<<g, 256, 0, stream>>>(fb, Wt, in_idx, outidx, valid, out, N);

        stats_k<<<256, 256, 0, stream>>>(out, stats, N);
        bngelu_k<<<(N * COUT / 4 + 255) / 256, 256, 0, stream>>>(out, stats, gamma, beta,
                                                                 1.0f / (float)N, N * COUT / 4);
    }
}

// Round 18
// 162.942 us; speedup vs baseline: 2.6348x; 1.0285x over previous
//
#include <hip/hip_runtime.h>

typedef unsigned short u16;
typedef unsigned int u32;
typedef unsigned long long u64;
using f32x4 = __attribute__((ext_vector_type(4))) float;
using bf16x8 = __attribute__((ext_vector_type(8))) short;

#define CIN 128
#define COUT 128
#define BM 128
#define LDA 136  // padded LDS row stride for Asub in fallback kernel only

__device__ inline u16 bf16rn(float f) {
    union { float f; u32 u; } v; v.f = f;
    u32 u = v.u;
    u += 0x7FFFu + ((u >> 16) & 1u);   // round-to-nearest-even
    return (u16)(u >> 16);
}

// ---------------- fallback-path precasts (also used as prep_k bodies) ----------------
__global__ void precast_feats_k(const float* __restrict__ in, u16* __restrict__ out, int total8) {
    int i = blockIdx.x * blockDim.x + threadIdx.x;
    if (i >= total8) return;
    const float4* p = (const float4*)in + 2 * (size_t)i;
    float4 a = p[0], b = p[1];
    u32 o0 = (u32)bf16rn(a.x) | ((u32)bf16rn(a.y) << 16);
    u32 o1 = (u32)bf16rn(a.z) | ((u32)bf16rn(a.w) << 16);
    u32 o2 = (u32)bf16rn(b.x) | ((u32)bf16rn(b.y) << 16);
    u32 o3 = (u32)bf16rn(b.z) | ((u32)bf16rn(b.w) << 16);
    ((uint4*)out)[i] = make_uint4(o0, o1, o2, o3);
}

// Wt fragment-linear layout: Wt[k][frag][lane][e], frag = cn*4+kk (32 frags).
// Element = W[k][c][d], d = cn*16 + (lane&15), c = kk*32 + (lane>>4)*8 + e.
// LDS staging is a pure linear memcpy; inner ds_read_b128 at lane*16B is
// conflict-free (verified r11: SQ_LDS_BANK_CONFLICT 5.4M -> 0).
__global__ void precast_w_k(const float* __restrict__ W, u16* __restrict__ Wt, int total) {
    int i = blockIdx.x * blockDim.x + threadIdx.x;
    if (i >= total) return;
    int k = i >> 14;
    int rem = i & 16383;
    int f = rem >> 9;          // frag 0..31
    int l = (rem >> 3) & 63;   // lane
    int e = rem & 7;
    int cn = f >> 2, kk = f & 3;
    int d = cn * 16 + (l & 15);
    int c = kk * 32 + ((l >> 4) << 3) + e;
    Wt[i] = bf16rn(W[(k << 14) + (c << 7) + d]);
}

// ---------------- fused prep: precast feats || precast W || hist ----------------
__global__ void prep_k(const float* __restrict__ feats, const float* __restrict__ W,
                       const int* __restrict__ oi, const int* __restrict__ valid,
                       u16* __restrict__ fb, u16* __restrict__ Wt,
                       int* __restrict__ cnt, int* __restrict__ pos,
                       int* __restrict__ bc0, int* __restrict__ bc1,
                       int total8, int totalw, int N, int E, int b0, int b1) {
    const int blk = blockIdx.x;
    const int tid = threadIdx.x;
    if (blk < b0) {
        int i = blk * 256 + tid;
        if (i >= total8) return;
        const float4* p = (const float4*)feats + 2 * (size_t)i;
        float4 a = p[0], q = p[1];
        u32 o0 = (u32)bf16rn(a.x) | ((u32)bf16rn(a.y) << 16);
        u32 o1 = (u32)bf16rn(a.z) | ((u32)bf16rn(a.w) << 16);
        u32 o2 = (u32)bf16rn(q.x) | ((u32)bf16rn(q.y) << 16);
        u32 o3 = (u32)bf16rn(q.z) | ((u32)bf16rn(q.w) << 16);
        ((uint4*)fb)[i] = make_uint4(o0, o1, o2, o3);
    } else if (blk < b0 + b1) {
        int i = (blk - b0) * 256 + tid;
        if (i >= totalw) return;
        int k = i >> 14;
        int rem = i & 16383;
        int f = rem >> 9;
        int l = (rem >> 3) & 63;
        int e = rem & 7;
        int cn = f >> 2, kk = f & 3;
        int d = cn * 16 + (l & 15);
        int c = kk * 32 + ((l >> 4) << 3) + e;
        Wt[i] = bf16rn(W[(k << 14) + (c << 7) + d]);
    } else {
        const int b = blk - b0 - b1;            // local hist block index
        const int e = b * 256 + tid;
        const int k0 = (b * 256) / N;
        bool v = false; bool g = false;
        if (e < E) {
            v = valid[e] > 0;
            g = (e >= (k0 + 1) * N);
            if (v) pos[e] = atomicAdd(&cnt[oi[e]], 1);
        }
        const int lane = tid & 63, wid = tid >> 6;
        u64 m0 = __ballot(v && !g);
        u64 m1 = __ballot(v && g);
        __shared__ int wt[4][2];
        if (lane == 0) { wt[wid][0] = __popcll(m0); wt[wid][1] = __popcll(m1); }
        __syncthreads();
        if (tid == 0) bc0[b] = wt[0][0] + wt[1][0] + wt[2][0] + wt[3][0];
        if (tid == 1) bc1[b] = wt[0][1] + wt[1][1] + wt[2][1] + wt[3][1];
    }
}

// ---------------- fallback-path hist (unfused) ----------------
__global__ void hist_k(const int* __restrict__ oi, const int* __restrict__ valid,
                       int* __restrict__ cnt, int* __restrict__ pos,
                       int* __restrict__ bc0, int* __restrict__ bc1, int N, int E) {
    const int tid = threadIdx.x;
    const int b = blockIdx.x;
    const int e = b * 256 + tid;
    const int k0 = (b * 256) / N;
    bool v = false; bool g = false;
    if (e < E) {
        v = valid[e] > 0;
        g = (e >= (k0 + 1) * N);
        if (v) pos[e] = atomicAdd(&cnt[oi[e]], 1);
    }
    const int lane = tid & 63, wid = tid >> 6;
    u64 m0 = __ballot(v && !g);
    u64 m1 = __ballot(v && g);
    __shared__ int wt[4][2];
    if (lane == 0) { wt[wid][0] = __popcll(m0); wt[wid][1] = __popcll(m1); }
    __syncthreads();
    if (tid == 0) bc0[b] = wt[0][0] + wt[1][0] + wt[2][0] + wt[3][0];
    if (tid == 1) bc1[b] = wt[0][1] + wt[1][1] + wt[2][1] + wt[3][1];
}

// ---- per-256-chunk sums of cnt[N] -> bsum (raw, NOT scanned) ----
__global__ void scan_sum_k(const int* __restrict__ cnt, int* __restrict__ bsum, int N) {
    __shared__ int red[256];
    int t = threadIdx.x;
    int i = blockIdx.x * 256 + t;
    red[t] = (i < N) ? cnt[i] : 0;
    __syncthreads();
    #pragma unroll
    for (int d = 128; d > 0; d >>= 1) {
        if (t < d) red[t] += red[t + d];
        __syncthreads();
    }
    if (t == 0) bsum[blockIdx.x] = red[0];
}

// fallback-path top scan (unfused path only)
__global__ void scan_top_k(int* __restrict__ bsum, int nb) {
    __shared__ int part[1024];
    int t = threadIdx.x;
    int v = (t < nb) ? bsum[t] : 0;
    part[t] = v;
    __syncthreads();
    for (int d = 1; d < 1024; d <<= 1) {
        int x = (t >= d) ? part[t - d] : 0;
        __syncthreads();
        part[t] += x;
        __syncthreads();
    }
    if (t < nb) bsum[t] = part[t] - v;   // exclusive
}

// ---------------- fused scan_apply || kscan (block-range split) ----------------
// scan_apply branch now computes its own base = sum(bsum[0..blockIdx.x)) from
// the RAW per-chunk sums (<=157 ints: one strided read/thread + 8-step LDS
// reduce) — removes the serializing 1-block scan_top dispatch (same class of
// win as r17's finalize removal).
__global__ void scan_apply_kscan_k(const int* __restrict__ cnt, const int* __restrict__ bsum,
                                   int* __restrict__ offs,
                                   const int* __restrict__ bc0, const int* __restrict__ bc1,
                                   int* __restrict__ base0, int* __restrict__ base1,
                                   int* __restrict__ kcount, int N, int nb) {
    const int t = threadIdx.x;
    __shared__ int part[256];
    if ((int)blockIdx.x < nb) {
        // phase 0: base = sum of preceding chunk sums
        int acc = 0;
        for (int j = t; j < (int)blockIdx.x; j += 256) acc += bsum[j];
        part[t] = acc;
        __syncthreads();
        #pragma unroll
        for (int d = 128; d > 0; d >>= 1) {
            if (t < d) part[t] += part[t + d];
            __syncthreads();
        }
        const int base = part[0];
        __syncthreads();   // before reusing part[]
        // phase 1: local exclusive scan (identical arithmetic to before)
        int i = blockIdx.x * 256 + t;
        int v = (i < N) ? cnt[i] : 0;
        part[t] = v;
        __syncthreads();
        #pragma unroll
        for (int d = 1; d < 256; d <<= 1) {
            int x = (t >= d) ? part[t - d] : 0;
            __syncthreads();
            part[t] += x;
            __syncthreads();
        }
        if (i < N) {
            int excl = base + part[t] - v;
            offs[i] = excl;
            if (i == N - 1) offs[N] = excl + v;
        }
    } else {
        const int k = blockIdx.x - nb;
        const int blo = (k * N) / 256;
        const int bhi = ((k + 1) * N - 1) / 256;
        const int len = bhi - blo + 1;        // <= 256 (guarded host-side)
        const int b = blo + t;
        int k0b = 0, contrib = 0;
        const bool inr = (t < len);
        if (inr) {
            k0b = (b * 256) / N;
            contrib = (k0b == k) ? bc0[b] : bc1[b];
        }
        part[t] = contrib;
        __syncthreads();
        #pragma unroll
        for (int d = 1; d < 256; d <<= 1) {
            int x = (t >= d) ? part[t - d] : 0;
            __syncthreads();
            part[t] += x;
            __syncthreads();
        }
        if (inr) {
            int excl = part[t] - contrib;
            if (k0b == k) base0[b] = excl; else base1[b] = excl;
            if (t == len - 1) kcount[k] = part[t];
        }
    }
}

// ---------------- rank: fully atomic-free ----------------
__global__ void rank_k(const int* __restrict__ oi, const int* __restrict__ ini,
                       const int* __restrict__ valid, const int* __restrict__ pos,
                       const int* __restrict__ offs,
                       const int* __restrict__ base0, const int* __restrict__ base1,
                       int* __restrict__ cin_arr, int* __restrict__ cpos_arr,
                       int N, int E, int cap) {
    const int tid = threadIdx.x;
    const int b = blockIdx.x;
    const int e = b * 256 + tid;
    const int k0 = (b * 256) / N;
    bool v = false; int k = 0, n = 0, ii = 0, p = 0;
    if (e < E) {
        v = valid[e] > 0;
        k = (e >= (k0 + 1) * N) ? k0 + 1 : k0;
        if (v) { n = oi[e]; ii = ini[e]; p = pos[e]; }
    }
    const int g = k - k0;   // 0 or 1
    const int lane = tid & 63, wid = tid >> 6;
    u64 m0 = __ballot(v && g == 0);
    u64 m1 = __ballot(v && g == 1);
    u64 lt = (1ull << lane) - 1ull;
    int r0 = __popcll(m0 & lt);
    int r1 = __popcll(m1 & lt);
    __shared__ int wt[4][2];
    if (lane == 0) { wt[wid][0] = __popcll(m0); wt[wid][1] = __popcll(m1); }
    __syncthreads();
    if (v) {
        int wbase = 0;
        #pragma unroll
        for (int w2 = 0; w2 < 4; ++w2) if (w2 < wid) wbase += wt[w2][g];
        int kb = g ? base1[b] : base0[b];
        int slot = kb + wbase + (g ? r1 : r0);
        int pg = offs[n] + p;
        cin_arr[k * N + slot] = ii;
        cpos_arr[k * N + slot] = (pg < cap) ? pg : (cap + n);
    }
}

// ---------------- phase A: gather + GEMM + sorted store (r13 verified best) ----------------
// 512 threads, 8 waves, 16 rows/wave, one 128-row tile per block (NO
// persistent loop: r14/r15 loop-carried variants spilled a0/acc to scratch —
// FETCH 61->600+ MB — and regressed 2.5x; this exact body measured 47 us,
// FETCH 61 MB, VGPR 32, 0 bank conflicts). B staged via linear memcpy of
// fragment-order Wt; A gathered into registers in MFMA layout before staging;
// cpos read post-MFMA.
// msg row layout: word w = 4*l15 + q holds packed bf16 cols (l15+32q, l15+32q+16)
__launch_bounds__(512, 6)
__global__ void convA_k(const u16* __restrict__ fb, const u16* __restrict__ Wt,
                        const int* __restrict__ cin_arr, const int* __restrict__ cpos_arr,
                        const int* __restrict__ kcount, u32* __restrict__ msg,
                        float* __restrict__ out, int N, int cap)
{
    const int k = blockIdx.y;
    const int kc = kcount[k];
    const int m0 = blockIdx.x * BM;
    if (m0 >= kc) return;

    __shared__ __align__(16) u16 Bsub[COUT * CIN];   // 32 KB, fragment-linear

    const int tid = threadIdx.x;
    const int wave = tid >> 6, lane = tid & 63;
    const int l15 = lane & 15, l4 = lane >> 4;
    const int base = k * N;

    // A fragments: global -> regs, MFMA layout. One 16-row set per wave.
    int r0 = m0 + wave * 16 + l15;
    int i0 = cin_arr[base + min(r0, kc - 1)];
    if (r0 >= kc) i0 = 0;   // read valid memory; result rows are discarded
    const u16* pa0 = fb + (size_t)i0 * CIN + l4 * 8;
    bf16x8 a0[4];
    #pragma unroll
    for (int kk = 0; kk < 4; ++kk)
        a0[kk] = *(const bf16x8*)(pa0 + kk * 32);

    // stage W[k] (fragment-order, 32 KB) into LDS: pure linear memcpy
    {
        const u16* wk = Wt + ((size_t)k << 14);
        #pragma unroll
        for (int j = 0; j < 4; ++j)
            *(uint4*)(Bsub + j * 4096 + tid * 8) = *(const uint4*)(wk + j * 4096 + tid * 8);
    }
    __syncthreads();

    f32x4 acc[8];
    #pragma unroll
    for (int y = 0; y < 8; ++y)
        acc[y] = (f32x4){0.f, 0.f, 0.f, 0.f};

    #pragma unroll
    for (int kk = 0; kk < 4; ++kk) {
        #pragma unroll
        for (int cn = 0; cn < 8; ++cn) {
            bf16x8 b = *(const bf16x8*)(Bsub + (((cn << 2) + kk) << 9) + lane * 8);
            acc[cn] = __builtin_amdgcn_mfma_f32_16x16x32_bf16(a0[kk], b, acc[cn], 0, 0, 0);
        }
    }

    #pragma unroll
    for (int j = 0; j < 4; ++j) {
        int rl = m0 + wave * 16 + l4 * 4 + j;
        if (rl >= kc) continue;
        int v = cpos_arr[base + rl];   // 16 lanes share each addr -> broadcast
        if (v < cap) {
            u32 w0 = (u32)bf16rn(acc[0][j]) | ((u32)bf16rn(acc[1][j]) << 16);
            u32 w1 = (u32)bf16rn(acc[2][j]) | ((u32)bf16rn(acc[3][j]) << 16);
            u32 w2 = (u32)bf16rn(acc[4][j]) | ((u32)bf16rn(acc[5][j]) << 16);
            u32 w3 = (u32)bf16rn(acc[6][j]) | ((u32)bf16rn(acc[7][j]) << 16);
            *(uint4*)(msg + (size_t)v * 64 + 4 * l15) = make_uint4(w0, w1, w2, w3);
        } else {
            int n = v - cap;
            float* dst = out + (size_t)n * COUT + l15;
            #pragma unroll
            for (int cn = 0; cn < 8; ++cn)
                atomicAdd(dst + cn * 16, acc[cn][j]);
        }
    }
}

// ---------------- phase B (wmode=1): uint4 segment-sum + fused stats ----------------
__global__ void convB_stats_k(const u32* __restrict__ msg, const int* __restrict__ offs,
                              float* __restrict__ out, float* __restrict__ stats,
                              int N, int cap, int nblk)
{
    const int tid = threadIdx.x;
    const int wave = tid >> 6, lane = tid & 63;
    const int sub = lane >> 4, l15 = lane & 15;
    const int colA = l15 + 32 * sub;
    float sA = 0.f, qA = 0.f, sB = 0.f, qB = 0.f;

    for (int n = blockIdx.x * 4 + wave; n < N; n += nblk * 4) {
        int s = min(offs[n], cap), e = min(offs[n + 1], cap);
        float a0 = 0.f, a1 = 0.f, a2 = 0.f, a3 = 0.f;
        float b0 = 0.f, b1 = 0.f, b2 = 0.f, b3 = 0.f;
        for (int r = s; r < e; r += 4) {
            int ent = r + sub;
            uint4 v = make_uint4(0u, 0u, 0u, 0u);
            if (ent < e) v = *(const uint4*)(msg + (size_t)ent * 64 + 4 * l15);
            a0 += __uint_as_float(v.x << 16); b0 += __uint_as_float(v.x & 0xFFFF0000u);
            a1 += __uint_as_float(v.y << 16); b1 += __uint_as_float(v.y & 0xFFFF0000u);
            a2 += __uint_as_float(v.z << 16); b2 += __uint_as_float(v.z & 0xFFFF0000u);
            a3 += __uint_as_float(v.w << 16); b3 += __uint_as_float(v.w & 0xFFFF0000u);
        }
        #define RED4(x) { x += __shfl_xor(x, 16, 64); x += __shfl_xor(x, 32, 64); }
        RED4(a0) RED4(a1) RED4(a2) RED4(a3)
        RED4(b0) RED4(b1) RED4(b2) RED4(b3)
        #undef RED4
        float va = (sub == 0) ? a0 : (sub == 1) ? a1 : (sub == 2) ? a2 : a3;
        float vb = (sub == 0) ? b0 : (sub == 1) ? b1 : (sub == 2) ? b2 : b3;
        float* po = out + (size_t)n * COUT;
        po[colA]      = va;
        po[colA + 16] = vb;
        sA += va; qA += va * va;
        sB += vb; qB += vb * vb;
    }

    __shared__ float st[4][64][4];
    st[wave][lane][0] = sA; st[wave][lane][1] = qA;
    st[wave][lane][2] = sB; st[wave][lane][3] = qB;
    __syncthreads();
    int lane2 = tid >> 2, slot = tid & 3;
    float sum = st[0][lane2][slot] + st[1][lane2][slot]
              + st[2][lane2][slot] + st[3][lane2][slot];
    int colb = (lane2 & 15) + 32 * (lane2 >> 4) + ((slot >= 2) ? 16 : 0);
    atomicAdd(&stats[((slot & 1) ? 128 : 0) + colb], sum);
}

// ---------------- phase B (wmode=0): += segment-sum (composes with atomics) ----
__global__ void convB_k(const u32* __restrict__ msg, const int* __restrict__ offs,
                        float* __restrict__ out, int N, int cap)
{
    int wave = threadIdx.x >> 6, lane = threadIdx.x & 63;
    int n = blockIdx.x * 4 + wave;
    if (n >= N) return;
    int s = min(offs[n], cap), e = min(offs[n + 1], cap);
    float a0 = 0.f, a1 = 0.f;
    int r = s;
    for (; r + 2 <= e; r += 2) {
        u32 v0 = msg[(size_t)r * 64 + lane];
        u32 v1 = msg[(size_t)(r + 1) * 64 + lane];
        a0 += __uint_as_float(v0 << 16) + __uint_as_float(v1 << 16);
        a1 += __uint_as_float(v0 & 0xFFFF0000u) + __uint_as_float(v1 & 0xFFFF0000u);
    }
    if (r < e) {
        u32 v0 = msg[(size_t)r * 64 + lane];
        a0 += __uint_as_float(v0 << 16);
        a1 += __uint_as_float(v0 & 0xFFFF0000u);
    }
    int c0 = (lane >> 2) + ((lane & 3) << 5);
    float* po = out + (size_t)n * COUT;
    po[c0]      += a0;
    po[c0 + 16] += a1;
}

// ---------------- fallback atomic conv (frag-linear Wt) ----------------
__launch_bounds__(256, 2)
__global__ void conv_k(const u16* __restrict__ fb, const u16* __restrict__ Wt,
                       const int* __restrict__ in_idx, const int* __restrict__ out_idx,
                       const int* __restrict__ valid, float* __restrict__ out, int N)
{
    __shared__ __align__(16) u16 Asub[BM * LDA];
    __shared__ __align__(16) u16 Bsub[COUT * CIN];   // fragment-linear
    __shared__ int orow[BM];

    const int tile = blockIdx.x;
    const int k = blockIdx.y;
    const int tid = threadIdx.x;
    const int m0 = tile * BM;

    {
        const u16* wk = Wt + ((size_t)k << 14);
        #pragma unroll
        for (int j = 0; j < 8; ++j)
            *(uint4*)(Bsub + j * 2048 + tid * 8) = *(const uint4*)(wk + j * 2048 + tid * 8);
    }
    {
        int r = tid >> 1, half = tid & 1;
        int m = m0 + r;
        int act = 0, ii = 0, oi = -1;
        if (m < N) {
            int base = k * N + m;
            act = valid[base];
            ii  = in_idx[base];
            oi  = out_idx[base];
        }
        if (half == 0) orow[r] = (m < N && act > 0) ? oi : -1;
        if (m < N && act > 0) {
            const u16* src = fb + (size_t)ii * CIN + half * 64;
            u16* dst = Asub + r * LDA + half * 64;
            #pragma unroll
            for (int j = 0; j < 8; ++j)
                *(uint4*)(dst + j * 8) = *(const uint4*)(src + j * 8);
        }
    }
    __syncthreads();

    const int wave = tid >> 6, lane = tid & 63;
    const int l15 = lane & 15, l4 = lane >> 4;

    f32x4 acc[2][8];
    #pragma unroll
    for (int x = 0; x < 2; ++x)
        #pragma unroll
        for (int y = 0; y < 8; ++y)
            acc[x][y] = (f32x4){0.f, 0.f, 0.f, 0.f};

    #pragma unroll
    for (int kk = 0; kk < 4; ++kk) {
        const int coff = kk * 32 + l4 * 8;
        bf16x8 a0 = *(const bf16x8*)(Asub + (wave * 32 + l15) * LDA + coff);
        bf16x8 a1 = *(const bf16x8*)(Asub + (wave * 32 + 16 + l15) * LDA + coff);
        #pragma unroll
        for (int cn = 0; cn < 8; ++cn) {
            bf16x8 b = *(const bf16x8*)(Bsub + (((cn << 2) + kk) << 9) + lane * 8);
            acc[0][cn] = __builtin_amdgcn_mfma_f32_16x16x32_bf16(a0, b, acc[0][cn], 0, 0, 0);
            acc[1][cn] = __builtin_amdgcn_mfma_f32_16x16x32_bf16(a1, b, acc[1][cn], 0, 0, 0);
        }
    }

    #pragma unroll
    for (int rm = 0; rm < 2; ++rm) {
        #pragma unroll
        for (int j = 0; j < 4; ++j) {
            int rl = wave * 32 + rm * 16 + l4 * 4 + j;
            int od = orow[rl];
            if (od >= 0) {
                float* dst = out + (size_t)od * COUT + l15;
                #pragma unroll
                for (int cn = 0; cn < 8; ++cn)
                    atomicAdd(dst + cn * 16, acc[rm][cn][j]);
            }
        }
    }
}

// ---------------- stats / BN+GELU ----------------
__global__ void stats_k(const float* __restrict__ out, float* __restrict__ stats, int N) {
    const int tid = threadIdx.x;
    const int col = tid & 127;
    const int pr = tid >> 7;
    float s = 0.f, sq = 0.f;
    for (int r = blockIdx.x * 2 + pr; r < N; r += gridDim.x * 2) {
        float v = out[(size_t)r * COUT + col];
        s += v; sq += v * v;
    }
    __shared__ float red[512];
    red[tid] = s;
    red[256 + tid] = sq;
    __syncthreads();
    if (tid < 128) {
        atomicAdd(&stats[col],       red[tid] + red[tid + 128]);
        atomicAdd(&stats[128 + col], red[256 + tid] + red[384 + tid]);
    }
}

// BN transform: sc/ofs computed once per BLOCK into LDS from raw sums —
// fp32-arithmetic-identical to the old finalize_k (bitwise-same output),
// amortized over 1024 elements/block. (r17: removing the 1-block finalize
// dispatch was -8 us.)
__global__ void bngelu_k(float* __restrict__ out, const float* __restrict__ stats,
                         const float* __restrict__ gamma, const float* __restrict__ beta,
                         float invN, int total4) {
    __shared__ float sc_s[128], of_s[128];
    int tid = threadIdx.x;
    if (tid < 128) {
        float mean = stats[tid] * invN;
        float var = stats[128 + tid] * invN - mean * mean;
        float sc = rsqrtf(var + 1e-5f) * gamma[tid];
        sc_s[tid] = sc;
        of_s[tid] = beta[tid] - mean * sc;
    }
    __syncthreads();
    int i = blockIdx.x * blockDim.x + tid;
    if (i >= total4) return;
    float4 v = ((const float4*)out)[i];
    int cb = (i << 2) & 127;
    float r[4] = {v.x, v.y, v.z, v.w};
    #pragma unroll
    for (int e = 0; e < 4; ++e) {
        int c = cb + e;
        float y = r[e] * sc_s[c] + of_s[c];
        r[e] = 0.5f * y * (1.0f + erff(y * 0.70710678118f));
    }
    ((float4*)out)[i] = make_float4(r[0], r[1], r[2], r[3]);
}

extern "C" void kernel_launch(void* const* d_in, const int* in_sizes, int n_in,
                              void* d_out, int out_size, void* d_ws, size_t ws_size,
                              hipStream_t stream) {
    const float* feats  = (const float*)d_in[0];
    const float* W      = (const float*)d_in[1];
    const float* gamma  = (const float*)d_in[2];
    const float* beta   = (const float*)d_in[3];
    const int*   in_idx = (const int*)d_in[4];
    const int*   outidx = (const int*)d_in[5];
    const int*   valid  = (const int*)d_in[6];
    const int N = in_sizes[0] / CIN;          // 40000
    const int K = in_sizes[1] / (CIN * COUT); // 27
    const int E = K * N;
    float* out = (float*)d_out;

    const int nb  = (N + 255) / 256;          // scan blocks (157) — must be <= 1024
    const int nbE = (E + 255) / 256;          // entry blocks (4219)

    const size_t fbB   = ((size_t)N * CIN * 2 + 255) & ~255ull;
    const size_t WtB   = ((size_t)K * CIN * COUT * 2 + 255) & ~255ull;
    const size_t cinB  = ((size_t)E * 4 + 255) & ~255ull;
    const size_t cposB = cinB;
    const size_t posB  = cinB;                                   // pos[E]
    const size_t cntB  = ((size_t)N * 4 + 255) & ~255ull;       // cnt[N]
    const size_t kcB   = 256;                                    // kcount[K]
    const size_t stB   = 2048;                                   // stats[512]
    const size_t offsB = ((size_t)(N + 1) * 4 + 255) & ~255ull;
    const size_t bsB   = ((size_t)nb * 4 + 255) & ~255ull;       // block sums
    const size_t nbEB  = ((size_t)nbE * 4 + 255) & ~255ull;      // bc0/bc1/base0/base1
    const size_t fixedB = fbB + WtB + cinB + cposB + posB + cntB + kcB + stB + offsB
                        + bsB + 4 * nbEB + 1024;

    int total8 = N * CIN / 8;
    int totalw = K * CIN * COUT;

    if (ws_size >= fixedB + (size_t)1024 * 256 && nb <= 1024 && nb + 1 <= 256) {
        long long capL = ((long long)ws_size - (long long)fixedB) / 256;
        if (capL > (long long)E) capL = E;
        const int cap = (int)capL;
        const int wmode = (cap >= E) ? 1 : 0;   // no overflow atomics possible

        char* w = (char*)d_ws;
        u32* msg      = (u32*)w;  w += (size_t)cap * 256;
        u16* fb       = (u16*)w;  w += fbB;
        u16* Wt       = (u16*)w;  w += WtB;
        int* cin_arr  = (int*)w;  w += cinB;
        int* cpos_arr = (int*)w;  w += cposB;
        int* pos      = (int*)w;  w += posB;
        int* cnt      = (int*)w;  w += cntB;   // cnt | kcount | stats contiguous
        int* kcount   = (int*)w;  w += kcB;
        float* stats  = (float*)w; w += stB;
        int* offs     = (int*)w;  w += offsB;
        int* bsum     = (int*)w;  w += bsB;
        int* bc0      = (int*)w;  w += nbEB;
        int* bc1      = (int*)w;  w += nbEB;
        int* base0    = (int*)w;  w += nbEB;
        int* base1    = (int*)w;

        if (!wmode)
            hipMemsetAsync(out, 0, (size_t)N * COUT * sizeof(float), stream);
        hipMemsetAsync(cnt, 0, cntB + kcB + stB, stream);

        const int b0 = (total8 + 255) / 256;
        const int b1 = (totalw + 255) / 256;
        prep_k<<<b0 + b1 + nbE, 256, 0, stream>>>(feats, W, outidx, valid, fb, Wt,
                                                  cnt, pos, bc0, bc1,
                                                  total8, totalw, N, E, b0, b1);
        scan_sum_k<<<nb, 256, 0, stream>>>(cnt, bsum, N);
        scan_apply_kscan_k<<<nb + K, 256, 0, stream>>>(cnt, bsum, offs, bc0, bc1,
                                                       base0, base1, kcount, N, nb);
        rank_k<<<nbE, 256, 0, stream>>>(outidx, in_idx, valid, pos, offs,
                                        base0, base1, cin_arr, cpos_arr, N, E, cap);

        dim3 gA((N + BM - 1) / BM, K);
        convA_k<<<gA, 512, 0, stream>>>(fb, Wt, cin_arr, cpos_arr, kcount, msg, out, N, cap);

        if (wmode) {
            const int nblk = 2048;
            convB_stats_k<<<nblk, 256, 0, stream>>>(msg, offs, out, stats, N, cap, nblk);
        } else {
            convB_k<<<(N + 3) / 4, 256, 0, stream>>>(msg, offs, out, N, cap);
            stats_k<<<256, 256, 0, stream>>>(out, stats, N);
        }

        bngelu_k<<<(N * COUT / 4 + 255) / 256, 256, 0, stream>>>(out, stats, gamma, beta,
                                                                 1.0f / (float)N, N * COUT / 4);
    } else {
        // minimal-ws fallback: atomic path (~11.4 MB)
        u16* fb = (u16*)d_ws;
        u16* Wt = fb + (size_t)N * CIN;
        float* stats = (float*)(Wt + (size_t)K * CIN * COUT);

        hipMemsetAsync(out, 0, (size_t)N * COUT * sizeof(float), stream);
        hipMemsetAsync(stats, 0, 256 * sizeof(float), stream);

        precast_feats_k<<<(total8 + 255) / 256, 256, 0, stream>>>(feats, fb, total8);
        precast_w_k<<<(totalw + 255) / 256, 256, 0, stream>>>(W, Wt, totalw);

        dim3 g((N + BM - 1) / BM, K);
        conv_k<<<g, 256, 0, stream>>>(fb, Wt, in_idx, outidx, valid, out, N);

        stats_k<<<256, 256, 0, stream>>>(out, stats, N);
        bngelu_k<<<(N * COUT / 4 + 255) / 256, 256, 0, stream>>>(out, stats, gamma, beta,
                                                                 1.0f / (float)N, N * COUT / 4);
    }
}